// Round 1
// baseline (1588.223 us; speedup 1.0000x reference)
//
#include <hip/hip_runtime.h>
#include <cstdint>
#include <cstddef>

// ---------------------------------------------------------------------------
// CellGraphSAGE: 3x (SAGE-mean conv -> BN -> ReLU)
// dims: 128 -> 512 -> 256 -> 128, N=50000 nodes, E=800000 edges
// Round 0: correct fp32 baseline. CSR-by-dst built per launch, fp32 SIMT GEMM.
// ---------------------------------------------------------------------------

#define EPS_BN 1e-5f

// ---------------- edge format hedge (int64 vs int32 storage) ---------------
// If edges are stored as int64 (little-endian, values < 2^31), then viewed as
// int32 every odd word is 0. Random int32 node ids make that impossible.
__global__ void detect_fmt_kernel(const int* __restrict__ edges, int* __restrict__ nz) {
    int t = threadIdx.x;  // single block of 256
    int cnt = 0;
    #pragma unroll
    for (int j = 0; j < 4; ++j) {
        int idx = 2 * (t * 4 + j) + 1;   // odd int32 words 1,3,...,2047
        if (edges[idx] != 0) cnt++;
    }
    if (cnt) atomicAdd(nz, cnt);
}

__device__ __forceinline__ void edge_sd(const int* __restrict__ p, int e, int ne,
                                        bool is64, int& s, int& d) {
    if (is64) { s = p[2 * e];  d = p[2 * ne + 2 * e]; }
    else      { s = p[e];      d = p[ne + e]; }
}

// ---------------- CSR build ------------------------------------------------
__global__ void count_deg_kernel(const int* __restrict__ edges, int ne,
                                 const int* __restrict__ nz, int* __restrict__ degi) {
    bool is64 = (*nz == 0);
    int e = blockIdx.x * 256 + threadIdx.x;
    if (e < ne) {
        int s, d; edge_sd(edges, e, ne, is64, s, d);
        atomicAdd(&degi[d], 1);
    }
}

__global__ void scan1_kernel(const int* __restrict__ degi, int n,
                             int* __restrict__ rowptr, int* __restrict__ bsums) {
    __shared__ int sh[1024];
    int t = threadIdx.x;
    int i = blockIdx.x * 1024 + t;
    int v = (i < n) ? degi[i] : 0;
    sh[t] = v;
    __syncthreads();
    for (int off = 1; off < 1024; off <<= 1) {
        int x = (t >= off) ? sh[t - off] : 0;
        __syncthreads();
        sh[t] += x;
        __syncthreads();
    }
    if (i < n) rowptr[i] = sh[t] - v;          // exclusive within chunk
    if (t == 1023) bsums[blockIdx.x] = sh[t];  // chunk total
}

__global__ void scan2_kernel(int* __restrict__ bsums, int nb,
                             int* __restrict__ rowptr, int n, int total) {
    if (threadIdx.x == 0 && blockIdx.x == 0) {
        int run = 0;
        for (int b = 0; b < nb; ++b) { int t = bsums[b]; bsums[b] = run; run += t; }
        rowptr[n] = total;
    }
}

__global__ void scan3_kernel(int* __restrict__ rowptr, int n,
                             const int* __restrict__ bsums, int* __restrict__ cursor) {
    int i = blockIdx.x * 1024 + threadIdx.x;
    if (i < n) {
        int v = rowptr[i] + bsums[blockIdx.x];
        rowptr[i] = v;
        cursor[i] = v;
    }
}

__global__ void scatter_kernel(const int* __restrict__ edges, int ne,
                               const int* __restrict__ nz,
                               int* __restrict__ cursor, int* __restrict__ csr_src) {
    bool is64 = (*nz == 0);
    int e = blockIdx.x * 256 + threadIdx.x;
    if (e < ne) {
        int s, d; edge_sd(edges, e, ne, is64, s, d);
        int pos = atomicAdd(&cursor[d], 1);
        csr_src[pos] = s;
    }
}

// ---------------- aggregation: mean over in-neighbors ----------------------
// grid = n_nodes blocks, blockDim = din (128/256/512). One thread per column.
__global__ void aggregate_kernel(const float* __restrict__ h, float* __restrict__ mean,
                                 const int* __restrict__ rowptr,
                                 const int* __restrict__ csr_src) {
    int n = blockIdx.x;
    int t = threadIdx.x;
    int din = blockDim.x;
    int e0 = rowptr[n], e1 = rowptr[n + 1];
    float acc = 0.f;
    for (int e = e0; e < e1; ++e) {
        int s = csr_src[e];
        acc += h[(size_t)s * din + t];
    }
    int deg = e1 - e0;
    float scale = 1.0f / (float)(deg > 1 ? deg : 1);
    mean[(size_t)n * din + t] = acc * scale;
}

// ---------------- GEMM: C = A1@B1 + A2@B2 + bias ---------------------------
// A1,A2: N x K row-major; B1,B2: K x Dout row-major. 64x64 tile, BK=16, 4x4/thread.
__global__ __launch_bounds__(256) void gemm2_kernel(
    const float* __restrict__ A1, const float* __restrict__ B1,
    const float* __restrict__ A2, const float* __restrict__ B2,
    const float* __restrict__ bias, float* __restrict__ C,
    int N, int K, int Dout) {
    __shared__ float As[16][68];  // transposed: As[k][row]
    __shared__ float Bs[16][68];  // Bs[k][col]
    const int tid = threadIdx.x;
    const int tx = tid & 15;      // col group
    const int ty = tid >> 4;      // row group
    const int rowBase = blockIdx.y * 64;
    const int colBase = blockIdx.x * 64;
    float acc[4][4] = {};

    for (int pass = 0; pass < 2; ++pass) {
        const float* __restrict__ A = pass ? A2 : A1;
        const float* __restrict__ B = pass ? B2 : B1;
        for (int k0 = 0; k0 < K; k0 += 16) {
            // stage loads into registers
            int arow = tid >> 2, ak = (tid & 3) << 2;
            int grow = rowBase + arow;
            float4 av = make_float4(0.f, 0.f, 0.f, 0.f);
            if (grow < N) av = *(const float4*)(A + (size_t)grow * K + k0 + ak);
            int brow = tid >> 4, bc = (tid & 15) << 2;
            float4 bv = *(const float4*)(B + (size_t)(k0 + brow) * Dout + colBase + bc);
            __syncthreads();  // protect LDS from previous iteration's readers
            As[ak + 0][arow] = av.x;
            As[ak + 1][arow] = av.y;
            As[ak + 2][arow] = av.z;
            As[ak + 3][arow] = av.w;
            *(float4*)&Bs[brow][bc] = bv;
            __syncthreads();
            #pragma unroll
            for (int kk = 0; kk < 16; ++kk) {
                float a[4], b[4];
                #pragma unroll
                for (int i = 0; i < 4; ++i) a[i] = As[kk][ty * 4 + i];
                #pragma unroll
                for (int j = 0; j < 4; ++j) b[j] = Bs[kk][tx * 4 + j];
                #pragma unroll
                for (int i = 0; i < 4; ++i)
                    #pragma unroll
                    for (int j = 0; j < 4; ++j) acc[i][j] += a[i] * b[j];
            }
        }
    }

    #pragma unroll
    for (int i = 0; i < 4; ++i) {
        int row = rowBase + ty * 4 + i;
        if (row < N) {
            int col = colBase + tx * 4;
            float4 o;
            o.x = acc[i][0] + bias[col + 0];
            o.y = acc[i][1] + bias[col + 1];
            o.z = acc[i][2] + bias[col + 2];
            o.w = acc[i][3] + bias[col + 3];
            *(float4*)(C + (size_t)row * Dout + col) = o;
        }
    }
}

// ---------------- BN stats + apply ----------------------------------------
// block = (64,4) = 256 threads; grid = (D/64, 128)
__global__ void colstats_kernel(const float* __restrict__ h, int N, int D,
                                float* __restrict__ sum, float* __restrict__ sumsq) {
    int col = blockIdx.x * 64 + (threadIdx.x & 63);
    int lane = threadIdx.x >> 6;  // 0..3
    float s = 0.f, s2 = 0.f;
    int stride = gridDim.y * 4;
    for (int r = blockIdx.y * 4 + lane; r < N; r += stride) {
        float v = h[(size_t)r * D + col];
        s += v;
        s2 += v * v;
    }
    atomicAdd(&sum[col], s);
    atomicAdd(&sumsq[col], s2);
}

__global__ void bn_relu_kernel(float* __restrict__ h, int N, int D,
                               const float* __restrict__ sum, const float* __restrict__ sumsq,
                               const float* __restrict__ g, const float* __restrict__ b) {
    size_t idx = (size_t)blockIdx.x * blockDim.x + threadIdx.x;
    if (idx >= (size_t)N * D) return;
    int col = (int)(idx & (size_t)(D - 1));  // D is a power of two
    float m = sum[col] / (float)N;
    float var = sumsq[col] / (float)N - m * m;
    float inv = rsqrtf(var + EPS_BN);
    float v = h[idx];
    v = g[col] * (v - m) * inv + b[col];
    h[idx] = v > 0.f ? v : 0.f;
}

// ---------------------------------------------------------------------------
extern "C" void kernel_launch(void* const* d_in, const int* in_sizes, int n_in,
                              void* d_out, int out_size, void* d_ws, size_t ws_size,
                              hipStream_t stream) {
    const float* x     = (const float*)d_in[0];
    const int*   edges = (const int*)d_in[1];
    const float* Wl0 = (const float*)d_in[2];
    const float* bl0 = (const float*)d_in[3];
    const float* Wr0 = (const float*)d_in[4];
    const float* g0  = (const float*)d_in[5];
    const float* b0  = (const float*)d_in[6];
    const float* Wl1 = (const float*)d_in[7];
    const float* bl1 = (const float*)d_in[8];
    const float* Wr1 = (const float*)d_in[9];
    const float* g1  = (const float*)d_in[10];
    const float* b1  = (const float*)d_in[11];
    const float* Wl2 = (const float*)d_in[12];
    const float* bl2 = (const float*)d_in[13];
    const float* Wr2 = (const float*)d_in[14];
    const float* g2  = (const float*)d_in[15];
    const float* b2  = (const float*)d_in[16];

    const int D0 = 128, D1 = 512, D2 = 256, D3 = 128;
    const int n  = in_sizes[0] / D0;   // 50000
    const int ne = in_sizes[1] / 2;    // 800000

    // ---- workspace layout ----
    char* base = (char*)d_ws;
    size_t off = 0;
    auto alloc = [&](size_t bytes) -> char* {
        char* p = base + off;
        off = (off + bytes + 255) & ~(size_t)255;
        return p;
    };
    int*   nzflag   = (int*)alloc(4);
    int*   degi     = (int*)alloc((size_t)n * 4);
    int*   rowptr   = (int*)alloc((size_t)(n + 1) * 4);
    int*   cursor   = (int*)alloc((size_t)n * 4);
    int*   csr_src  = (int*)alloc((size_t)ne * 4);
    int*   bsums    = (int*)alloc(64 * 4);
    float* stats    = (float*)alloc(6 * 512 * 4);  // per-layer [sum(512)|sumsq(512)]
    float* meanbuf  = (float*)alloc((size_t)n * 512 * 4);
    float* h1       = (float*)alloc((size_t)n * 512 * 4);
    float* h2       = (float*)alloc((size_t)n * 256 * 4);
    float* out      = (float*)d_out;
    (void)ws_size; (void)n_in; (void)out_size;

    // ---- zero-init (harness poisons ws with 0xAA before every launch) ----
    hipMemsetAsync(nzflag, 0, 4, stream);
    hipMemsetAsync(degi, 0, (size_t)n * 4, stream);
    hipMemsetAsync(stats, 0, 6 * 512 * 4, stream);

    // ---- edge format detection + CSR build (shared by all 3 layers) ----
    detect_fmt_kernel<<<1, 256, 0, stream>>>(edges, nzflag);
    count_deg_kernel<<<(ne + 255) / 256, 256, 0, stream>>>(edges, ne, nzflag, degi);
    int nscan = (n + 1023) / 1024;  // 49
    scan1_kernel<<<nscan, 1024, 0, stream>>>(degi, n, rowptr, bsums);
    scan2_kernel<<<1, 64, 0, stream>>>(bsums, nscan, rowptr, n, ne);
    scan3_kernel<<<nscan, 1024, 0, stream>>>(rowptr, n, bsums, cursor);
    scatter_kernel<<<(ne + 255) / 256, 256, 0, stream>>>(edges, ne, nzflag, cursor, csr_src);

    // ---- layer 0: 128 -> 512 ----
    aggregate_kernel<<<n, D0, 0, stream>>>(x, meanbuf, rowptr, csr_src);
    gemm2_kernel<<<dim3(D1 / 64, (n + 63) / 64), 256, 0, stream>>>(
        meanbuf, Wl0, x, Wr0, bl0, h1, n, D0, D1);
    colstats_kernel<<<dim3(D1 / 64, 128), 256, 0, stream>>>(h1, n, D1, stats + 0 * 1024, stats + 0 * 1024 + 512);
    bn_relu_kernel<<<((size_t)n * D1 + 255) / 256, 256, 0, stream>>>(
        h1, n, D1, stats + 0 * 1024, stats + 0 * 1024 + 512, g0, b0);

    // ---- layer 1: 512 -> 256 ----
    aggregate_kernel<<<n, D1, 0, stream>>>(h1, meanbuf, rowptr, csr_src);
    gemm2_kernel<<<dim3(D2 / 64, (n + 63) / 64), 256, 0, stream>>>(
        meanbuf, Wl1, h1, Wr1, bl1, h2, n, D1, D2);
    colstats_kernel<<<dim3(D2 / 64, 128), 256, 0, stream>>>(h2, n, D2, stats + 1 * 1024, stats + 1 * 1024 + 512);
    bn_relu_kernel<<<((size_t)n * D2 + 255) / 256, 256, 0, stream>>>(
        h2, n, D2, stats + 1 * 1024, stats + 1 * 1024 + 512, g1, b1);

    // ---- layer 2: 256 -> 128 ----
    aggregate_kernel<<<n, D2, 0, stream>>>(h2, meanbuf, rowptr, csr_src);
    gemm2_kernel<<<dim3(D3 / 64, (n + 63) / 64), 256, 0, stream>>>(
        meanbuf, Wl2, h2, Wr2, bl2, out, n, D2, D3);
    colstats_kernel<<<dim3(D3 / 64, 128), 256, 0, stream>>>(out, n, D3, stats + 2 * 1024, stats + 2 * 1024 + 512);
    bn_relu_kernel<<<((size_t)n * D3 + 255) / 256, 256, 0, stream>>>(
        out, n, D3, stats + 2 * 1024, stats + 2 * 1024 + 512, g2, b2);
}

// Round 2
// 989.497 us; speedup vs baseline: 1.6051x; 1.6051x over previous
//
#include <hip/hip_runtime.h>
#include <cstdint>
#include <cstddef>

// ---------------------------------------------------------------------------
// CellGraphSAGE: 3x (SAGE-mean conv -> BN -> ReLU)
// dims: 128 -> 512 -> 256 -> 128, N=50000 nodes, E=800000 edges
// Round 2: bf16 MFMA GEMM (128x128 tile, 16x16x32 bf16 mfma) + bf16
// activations for the edge gathers. fp32 accumulation everywhere.
// ---------------------------------------------------------------------------

#define EPS_BN 1e-5f

typedef unsigned short ushort_t;
typedef __attribute__((ext_vector_type(8))) short short8;
typedef __attribute__((ext_vector_type(4))) float float4v;

__device__ __forceinline__ float bf2f(ushort_t u) {
    union { unsigned int i; float f; } v; v.i = ((unsigned int)u) << 16; return v.f;
}
__device__ __forceinline__ ushort_t f2bf(float f) {
    union { float f; unsigned int i; } v; v.f = f;
    unsigned int r = v.i + 0x7fffu + ((v.i >> 16) & 1u);  // RNE
    return (ushort_t)(r >> 16);
}

// ---------------- edge format hedge (int64 vs int32 storage) ---------------
__global__ void detect_fmt_kernel(const int* __restrict__ edges, int* __restrict__ nz) {
    int t = threadIdx.x;  // single block of 256
    int cnt = 0;
    #pragma unroll
    for (int j = 0; j < 4; ++j) {
        int idx = 2 * (t * 4 + j) + 1;
        if (edges[idx] != 0) cnt++;
    }
    if (cnt) atomicAdd(nz, cnt);
}

__device__ __forceinline__ void edge_sd(const int* __restrict__ p, int e, int ne,
                                        bool is64, int& s, int& d) {
    if (is64) { s = p[2 * e];  d = p[2 * ne + 2 * e]; }
    else      { s = p[e];      d = p[ne + e]; }
}

// ---------------- CSR build ------------------------------------------------
__global__ void count_deg_kernel(const int* __restrict__ edges, int ne,
                                 const int* __restrict__ nz, int* __restrict__ degi) {
    bool is64 = (*nz == 0);
    int e = blockIdx.x * 256 + threadIdx.x;
    if (e < ne) {
        int s, d; edge_sd(edges, e, ne, is64, s, d);
        atomicAdd(&degi[d], 1);
    }
}

__global__ void scan1_kernel(const int* __restrict__ degi, int n,
                             int* __restrict__ rowptr, int* __restrict__ bsums) {
    __shared__ int sh[1024];
    int t = threadIdx.x;
    int i = blockIdx.x * 1024 + t;
    int v = (i < n) ? degi[i] : 0;
    sh[t] = v;
    __syncthreads();
    for (int off = 1; off < 1024; off <<= 1) {
        int x = (t >= off) ? sh[t - off] : 0;
        __syncthreads();
        sh[t] += x;
        __syncthreads();
    }
    if (i < n) rowptr[i] = sh[t] - v;
    if (t == 1023) bsums[blockIdx.x] = sh[t];
}

__global__ void scan2_kernel(int* __restrict__ bsums, int nb,
                             int* __restrict__ rowptr, int n, int total) {
    if (threadIdx.x == 0 && blockIdx.x == 0) {
        int run = 0;
        for (int b = 0; b < nb; ++b) { int t = bsums[b]; bsums[b] = run; run += t; }
        rowptr[n] = total;
    }
}

__global__ void scan3_kernel(int* __restrict__ rowptr, int n,
                             const int* __restrict__ bsums, int* __restrict__ cursor) {
    int i = blockIdx.x * 1024 + threadIdx.x;
    if (i < n) {
        int v = rowptr[i] + bsums[blockIdx.x];
        rowptr[i] = v;
        cursor[i] = v;
    }
}

__global__ void scatter_kernel(const int* __restrict__ edges, int ne,
                               const int* __restrict__ nz,
                               int* __restrict__ cursor, int* __restrict__ csr_src) {
    bool is64 = (*nz == 0);
    int e = blockIdx.x * 256 + threadIdx.x;
    if (e < ne) {
        int s, d; edge_sd(edges, e, ne, is64, s, d);
        int pos = atomicAdd(&cursor[d], 1);
        csr_src[pos] = s;
    }
}

// ---------------- conversions ----------------------------------------------
__global__ void f2b_kernel(const float* __restrict__ in, ushort_t* __restrict__ out, int n) {
    int i = blockIdx.x * 256 + threadIdx.x;
    if (i < n) out[i] = f2bf(in[i]);
}

// WT[n][k]: k<K1 -> Wl[k][n], else Wr[k-K1][n]; bf16
__global__ void prep_wt_kernel(const float* __restrict__ Wl, const float* __restrict__ Wr,
                               ushort_t* __restrict__ WT, int K1, int Dout) {
    int idx = blockIdx.x * 256 + threadIdx.x;
    int K2 = 2 * K1;
    if (idx >= Dout * K2) return;
    int n = idx / K2, k = idx - n * K2;
    float v = (k < K1) ? Wl[(size_t)k * Dout + n] : Wr[(size_t)(k - K1) * Dout + n];
    WT[idx] = f2bf(v);
}

// ---------------- aggregation: mean over in-neighbors (bf16) ---------------
// grid = n_nodes blocks, blockDim = din/2. Each thread handles 2 columns.
__global__ void aggregate_bf16_kernel(const ushort_t* __restrict__ h, ushort_t* __restrict__ mean,
                                      const int* __restrict__ rowptr,
                                      const int* __restrict__ csr_src) {
    int node = blockIdx.x;
    int t = threadIdx.x;
    int din = blockDim.x * 2;
    int e0 = rowptr[node], e1 = rowptr[node + 1];
    float a0 = 0.f, a1 = 0.f;
    for (int e = e0; e < e1; ++e) {
        int s = csr_src[e];
        unsigned int v = *(const unsigned int*)(h + (size_t)s * din + 2 * t);
        a0 += bf2f((ushort_t)(v & 0xffffu));
        a1 += bf2f((ushort_t)(v >> 16));
    }
    int deg = e1 - e0;
    float scale = 1.0f / (float)(deg > 1 ? deg : 1);
    unsigned int o = (unsigned int)f2bf(a0 * scale) | ((unsigned int)f2bf(a1 * scale) << 16);
    *(unsigned int*)(mean + (size_t)node * din + 2 * t) = o;
}

// ---------------- MFMA GEMM: C = [A1|A2] @ WT^T + bias ---------------------
// A1,A2: N x K1 bf16 row-major. WT: Dout x 2K1 bf16 row-major (pre-transposed).
// C: N x Dout fp32. 128x128 tile per block (4 waves, each 64x64), BK=32.
#define PAD_STRIDE 40  // shorts; 80B row stride -> <=2-way LDS bank aliasing
__global__ __launch_bounds__(256) void gemm_mfma_kernel(
    const ushort_t* __restrict__ A1, const ushort_t* __restrict__ A2,
    const ushort_t* __restrict__ WT, const float* __restrict__ bias,
    float* __restrict__ C, int N, int K1, int Dout) {
    __shared__ short As[128 * PAD_STRIDE];
    __shared__ short Bs[128 * PAD_STRIDE];

    const int tid = threadIdx.x;
    const int wave = tid >> 6;
    const int lane = tid & 63;
    const int quad = lane >> 4;
    const int l15 = lane & 15;
    const int rowBase = blockIdx.y * 128;
    const int colBase = blockIdx.x * 128;
    const int wm = (wave >> 1) * 64;  // wave row offset within tile
    const int wn = (wave & 1) * 64;   // wave col offset

    float4v acc[4][4];
    #pragma unroll
    for (int i = 0; i < 4; ++i)
        #pragma unroll
        for (int j = 0; j < 4; ++j)
            acc[i][j] = (float4v){0.f, 0.f, 0.f, 0.f};

    const int K2 = 2 * K1;
    const int nkt = K2 / 32;
    const int khalf = K1 / 32;
    const int c0 = tid * 2;  // this thread's two 16B chunks (of 512 per tile)

    for (int kt = 0; kt < nkt; ++kt) {
        const ushort_t* Asrc;
        int kg;
        if (kt < khalf) { Asrc = A1; kg = kt * 32; }
        else            { Asrc = A2; kg = (kt - khalf) * 32; }
        const int kw = kt * 32;

        float4 a_ld[2], b_ld[2];
        #pragma unroll
        for (int u = 0; u < 2; ++u) {
            int c = c0 + u;
            int r = c >> 2, off = (c & 3) * 8;
            int grow = rowBase + r;
            a_ld[u] = (grow < N) ? *(const float4*)(Asrc + (size_t)grow * K1 + kg + off)
                                 : make_float4(0.f, 0.f, 0.f, 0.f);
            b_ld[u] = *(const float4*)(WT + (size_t)(colBase + r) * K2 + kw + off);
        }
        __syncthreads();  // protect LDS from previous iteration's readers
        #pragma unroll
        for (int u = 0; u < 2; ++u) {
            int c = c0 + u;
            int r = c >> 2, off = (c & 3) * 8;
            *(float4*)&As[r * PAD_STRIDE + off] = a_ld[u];
            *(float4*)&Bs[r * PAD_STRIDE + off] = b_ld[u];
        }
        __syncthreads();

        short8 af[4], bf[4];
        #pragma unroll
        for (int i = 0; i < 4; ++i)
            af[i] = *(const short8*)&As[(wm + i * 16 + l15) * PAD_STRIDE + quad * 8];
        #pragma unroll
        for (int j = 0; j < 4; ++j)
            bf[j] = *(const short8*)&Bs[(wn + j * 16 + l15) * PAD_STRIDE + quad * 8];

        #pragma unroll
        for (int i = 0; i < 4; ++i)
            #pragma unroll
            for (int j = 0; j < 4; ++j)
                acc[i][j] = __builtin_amdgcn_mfma_f32_16x16x32_bf16(af[i], bf[j], acc[i][j], 0, 0, 0);
    }

    // epilogue: C[row][col] = acc + bias[col]
    #pragma unroll
    for (int j = 0; j < 4; ++j) {
        int col = colBase + wn + j * 16 + l15;
        float bv = bias[col];
        #pragma unroll
        for (int i = 0; i < 4; ++i) {
            int rowb = rowBase + wm + i * 16 + quad * 4;
            #pragma unroll
            for (int r = 0; r < 4; ++r) {
                int row = rowb + r;
                if (row < N) C[(size_t)row * Dout + col] = acc[i][j][r] + bv;
            }
        }
    }
}

// ---------------- BN stats + apply ----------------------------------------
__global__ void colstats_kernel(const float* __restrict__ h, int N, int D,
                                float* __restrict__ sum, float* __restrict__ sumsq) {
    int col = blockIdx.x * 64 + (threadIdx.x & 63);
    int lane = threadIdx.x >> 6;  // 0..3
    float s = 0.f, s2 = 0.f;
    int stride = gridDim.y * 4;
    for (int r = blockIdx.y * 4 + lane; r < N; r += stride) {
        float v = h[(size_t)r * D + col];
        s += v;
        s2 += v * v;
    }
    atomicAdd(&sum[col], s);
    atomicAdd(&sumsq[col], s2);
}

// fp32 -> bf16 (intermediate layers)
__global__ void bn_relu_bf16_kernel(const float* __restrict__ h, ushort_t* __restrict__ hb,
                                    int N, int D,
                                    const float* __restrict__ sum, const float* __restrict__ sumsq,
                                    const float* __restrict__ g, const float* __restrict__ b) {
    size_t idx = (size_t)blockIdx.x * blockDim.x + threadIdx.x;
    if (idx >= (size_t)N * D) return;
    int col = (int)(idx & (size_t)(D - 1));
    float m = sum[col] / (float)N;
    float var = sumsq[col] / (float)N - m * m;
    float inv = rsqrtf(var + EPS_BN);
    float v = h[idx];
    v = g[col] * (v - m) * inv + b[col];
    hb[idx] = f2bf(v > 0.f ? v : 0.f);
}

// fp32 in-place (final layer -> d_out)
__global__ void bn_relu_kernel(float* __restrict__ h, int N, int D,
                               const float* __restrict__ sum, const float* __restrict__ sumsq,
                               const float* __restrict__ g, const float* __restrict__ b) {
    size_t idx = (size_t)blockIdx.x * blockDim.x + threadIdx.x;
    if (idx >= (size_t)N * D) return;
    int col = (int)(idx & (size_t)(D - 1));
    float m = sum[col] / (float)N;
    float var = sumsq[col] / (float)N - m * m;
    float inv = rsqrtf(var + EPS_BN);
    float v = h[idx];
    v = g[col] * (v - m) * inv + b[col];
    h[idx] = v > 0.f ? v : 0.f;
}

// ---------------------------------------------------------------------------
extern "C" void kernel_launch(void* const* d_in, const int* in_sizes, int n_in,
                              void* d_out, int out_size, void* d_ws, size_t ws_size,
                              hipStream_t stream) {
    const float* x     = (const float*)d_in[0];
    const int*   edges = (const int*)d_in[1];
    const float* Wl0 = (const float*)d_in[2];
    const float* bl0 = (const float*)d_in[3];
    const float* Wr0 = (const float*)d_in[4];
    const float* g0  = (const float*)d_in[5];
    const float* b0  = (const float*)d_in[6];
    const float* Wl1 = (const float*)d_in[7];
    const float* bl1 = (const float*)d_in[8];
    const float* Wr1 = (const float*)d_in[9];
    const float* g1  = (const float*)d_in[10];
    const float* b1  = (const float*)d_in[11];
    const float* Wl2 = (const float*)d_in[12];
    const float* bl2 = (const float*)d_in[13];
    const float* Wr2 = (const float*)d_in[14];
    const float* g2  = (const float*)d_in[15];
    const float* b2  = (const float*)d_in[16];

    const int D0 = 128, D1 = 512, D2 = 256, D3 = 128;
    const int n  = in_sizes[0] / D0;   // 50000
    const int ne = in_sizes[1] / 2;    // 800000

    // ---- workspace layout ----
    char* base = (char*)d_ws;
    size_t off = 0;
    auto alloc = [&](size_t bytes) -> char* {
        char* p = base + off;
        off = (off + bytes + 255) & ~(size_t)255;
        return p;
    };
    int*      nzflag  = (int*)alloc(4);
    int*      degi    = (int*)alloc((size_t)n * 4);
    int*      rowptr  = (int*)alloc((size_t)(n + 1) * 4);
    int*      cursor  = (int*)alloc((size_t)n * 4);
    int*      csr_src = (int*)alloc((size_t)ne * 4);
    int*      bsums   = (int*)alloc(64 * 4);
    float*    stats   = (float*)alloc(6 * 512 * 4);
    ushort_t* xb      = (ushort_t*)alloc((size_t)n * D0 * 2);
    ushort_t* mb      = (ushort_t*)alloc((size_t)n * 512 * 2);   // mean (max din)
    ushort_t* h1b     = (ushort_t*)alloc((size_t)n * D1 * 2);
    ushort_t* h2b     = (ushort_t*)alloc((size_t)n * D2 * 2);
    float*    hf      = (float*)alloc((size_t)n * 512 * 4);      // fp32 GEMM out (L0/L1)
    ushort_t* WT0     = (ushort_t*)alloc((size_t)D1 * 2 * D0 * 2);
    ushort_t* WT1     = (ushort_t*)alloc((size_t)D2 * 2 * D1 * 2);
    ushort_t* WT2     = (ushort_t*)alloc((size_t)D3 * 2 * D2 * 2);
    float*    out     = (float*)d_out;
    (void)ws_size; (void)n_in; (void)out_size;

    hipMemsetAsync(nzflag, 0, 4, stream);
    hipMemsetAsync(degi, 0, (size_t)n * 4, stream);
    hipMemsetAsync(stats, 0, 6 * 512 * 4, stream);

    // ---- edge format detection + CSR build ----
    detect_fmt_kernel<<<1, 256, 0, stream>>>(edges, nzflag);
    count_deg_kernel<<<(ne + 255) / 256, 256, 0, stream>>>(edges, ne, nzflag, degi);
    int nscan = (n + 1023) / 1024;
    scan1_kernel<<<nscan, 1024, 0, stream>>>(degi, n, rowptr, bsums);
    scan2_kernel<<<1, 64, 0, stream>>>(bsums, nscan, rowptr, n, ne);
    scan3_kernel<<<nscan, 1024, 0, stream>>>(rowptr, n, bsums, cursor);
    scatter_kernel<<<(ne + 255) / 256, 256, 0, stream>>>(edges, ne, nzflag, cursor, csr_src);

    // ---- prep: x -> bf16, weights -> transposed concat bf16 ----
    f2b_kernel<<<((size_t)n * D0 + 255) / 256, 256, 0, stream>>>(x, xb, n * D0);
    prep_wt_kernel<<<(D1 * 2 * D0 + 255) / 256, 256, 0, stream>>>(Wl0, Wr0, WT0, D0, D1);
    prep_wt_kernel<<<(D2 * 2 * D1 + 255) / 256, 256, 0, stream>>>(Wl1, Wr1, WT1, D1, D2);
    prep_wt_kernel<<<(D3 * 2 * D2 + 255) / 256, 256, 0, stream>>>(Wl2, Wr2, WT2, D2, D3);

    // ---- layer 0: 128 -> 512 ----
    aggregate_bf16_kernel<<<n, D0 / 2, 0, stream>>>(xb, mb, rowptr, csr_src);
    gemm_mfma_kernel<<<dim3(D1 / 128, (n + 127) / 128), 256, 0, stream>>>(
        mb, xb, WT0, bl0, hf, n, D0, D1);
    colstats_kernel<<<dim3(D1 / 64, 128), 256, 0, stream>>>(hf, n, D1, stats + 0 * 1024, stats + 0 * 1024 + 512);
    bn_relu_bf16_kernel<<<((size_t)n * D1 + 255) / 256, 256, 0, stream>>>(
        hf, h1b, n, D1, stats + 0 * 1024, stats + 0 * 1024 + 512, g0, b0);

    // ---- layer 1: 512 -> 256 ----
    aggregate_bf16_kernel<<<n, D1 / 2, 0, stream>>>(h1b, mb, rowptr, csr_src);
    gemm_mfma_kernel<<<dim3(D2 / 128, (n + 127) / 128), 256, 0, stream>>>(
        mb, h1b, WT1, bl1, hf, n, D1, D2);
    colstats_kernel<<<dim3(D2 / 64, 128), 256, 0, stream>>>(hf, n, D2, stats + 1 * 1024, stats + 1 * 1024 + 512);
    bn_relu_bf16_kernel<<<((size_t)n * D2 + 255) / 256, 256, 0, stream>>>(
        hf, h2b, n, D2, stats + 1 * 1024, stats + 1 * 1024 + 512, g1, b1);

    // ---- layer 2: 256 -> 128 ----
    aggregate_bf16_kernel<<<n, D2 / 2, 0, stream>>>(h2b, mb, rowptr, csr_src);
    gemm_mfma_kernel<<<dim3(D3 / 128, (n + 127) / 128), 256, 0, stream>>>(
        mb, h2b, WT2, bl2, out, n, D2, D3);
    colstats_kernel<<<dim3(D3 / 64, 128), 256, 0, stream>>>(out, n, D3, stats + 2 * 1024, stats + 2 * 1024 + 512);
    bn_relu_kernel<<<((size_t)n * D3 + 255) / 256, 256, 0, stream>>>(
        out, n, D3, stats + 2 * 1024, stats + 2 * 1024 + 512, g2, b2);
}

// Round 3
// 883.611 us; speedup vs baseline: 1.7974x; 1.1198x over previous
//
#include <hip/hip_runtime.h>
#include <cstdint>
#include <cstddef>

// ---------------------------------------------------------------------------
// CellGraphSAGE: 3x (SAGE-mean conv -> BN -> ReLU)
// dims: 128 -> 512 -> 256 -> 128, N=50000 nodes, E=800000 edges
// Round 3: project-then-aggregate for layers 1/2 (mean commutes with the
// linear map; gather dout-dim projections instead of din-dim activations),
// wave-per-node vectorized (16B/lane) gather kernel.
// ---------------------------------------------------------------------------

#define EPS_BN 1e-5f

typedef unsigned short ushort_t;
typedef __attribute__((ext_vector_type(8))) short short8;
typedef __attribute__((ext_vector_type(4))) float float4v;

__device__ __forceinline__ float bf2f(ushort_t u) {
    union { unsigned int i; float f; } v; v.i = ((unsigned int)u) << 16; return v.f;
}
__device__ __forceinline__ ushort_t f2bf(float f) {
    union { float f; unsigned int i; } v; v.f = f;
    unsigned int r = v.i + 0x7fffu + ((v.i >> 16) & 1u);  // RNE
    return (ushort_t)(r >> 16);
}

// ---------------- edge format hedge (int64 vs int32 storage) ---------------
__global__ void detect_fmt_kernel(const int* __restrict__ edges, int* __restrict__ nz) {
    int t = threadIdx.x;  // single block of 256
    int cnt = 0;
    #pragma unroll
    for (int j = 0; j < 4; ++j) {
        int idx = 2 * (t * 4 + j) + 1;
        if (edges[idx] != 0) cnt++;
    }
    if (cnt) atomicAdd(nz, cnt);
}

__device__ __forceinline__ void edge_sd(const int* __restrict__ p, int e, int ne,
                                        bool is64, int& s, int& d) {
    if (is64) { s = p[2 * e];  d = p[2 * ne + 2 * e]; }
    else      { s = p[e];      d = p[ne + e]; }
}

// ---------------- CSR build ------------------------------------------------
__global__ void count_deg_kernel(const int* __restrict__ edges, int ne,
                                 const int* __restrict__ nz, int* __restrict__ degi) {
    bool is64 = (*nz == 0);
    int e = blockIdx.x * 256 + threadIdx.x;
    if (e < ne) {
        int s, d; edge_sd(edges, e, ne, is64, s, d);
        atomicAdd(&degi[d], 1);
    }
}

__global__ void scan1_kernel(const int* __restrict__ degi, int n,
                             int* __restrict__ rowptr, int* __restrict__ bsums) {
    __shared__ int sh[1024];
    int t = threadIdx.x;
    int i = blockIdx.x * 1024 + t;
    int v = (i < n) ? degi[i] : 0;
    sh[t] = v;
    __syncthreads();
    for (int off = 1; off < 1024; off <<= 1) {
        int x = (t >= off) ? sh[t - off] : 0;
        __syncthreads();
        sh[t] += x;
        __syncthreads();
    }
    if (i < n) rowptr[i] = sh[t] - v;
    if (t == 1023) bsums[blockIdx.x] = sh[t];
}

__global__ void scan2_kernel(int* __restrict__ bsums, int nb,
                             int* __restrict__ rowptr, int n, int total) {
    if (threadIdx.x == 0 && blockIdx.x == 0) {
        int run = 0;
        for (int b = 0; b < nb; ++b) { int t = bsums[b]; bsums[b] = run; run += t; }
        rowptr[n] = total;
    }
}

__global__ void scan3_kernel(int* __restrict__ rowptr, int n,
                             const int* __restrict__ bsums, int* __restrict__ cursor) {
    int i = blockIdx.x * 1024 + threadIdx.x;
    if (i < n) {
        int v = rowptr[i] + bsums[blockIdx.x];
        rowptr[i] = v;
        cursor[i] = v;
    }
}

__global__ void scatter_kernel(const int* __restrict__ edges, int ne,
                               const int* __restrict__ nz,
                               int* __restrict__ cursor, int* __restrict__ csr_src) {
    bool is64 = (*nz == 0);
    int e = blockIdx.x * 256 + threadIdx.x;
    if (e < ne) {
        int s, d; edge_sd(edges, e, ne, is64, s, d);
        int pos = atomicAdd(&cursor[d], 1);
        csr_src[pos] = s;
    }
}

// ---------------- conversions ----------------------------------------------
__global__ void f2b_kernel(const float* __restrict__ in, ushort_t* __restrict__ out, int n) {
    int i = blockIdx.x * 256 + threadIdx.x;
    if (i < n) out[i] = f2bf(in[i]);
}

// dual-source transposed concat (layer 0): WT[n][k] k<K1 -> Wl[k][n] else Wr
__global__ void prep_wt_kernel(const float* __restrict__ Wl, const float* __restrict__ Wr,
                               ushort_t* __restrict__ WT, int K1, int Dout) {
    int idx = blockIdx.x * 256 + threadIdx.x;
    int K2 = 2 * K1;
    if (idx >= Dout * K2) return;
    int n = idx / K2, k = idx - n * K2;
    float v = (k < K1) ? Wl[(size_t)k * Dout + n] : Wr[(size_t)(k - K1) * Dout + n];
    WT[idx] = f2bf(v);
}

// single transpose: WT[n][k] = W[k][n]
__global__ void prep_wt1_kernel(const float* __restrict__ W, ushort_t* __restrict__ WT,
                                int K, int Dout) {
    int idx = blockIdx.x * 256 + threadIdx.x;
    if (idx >= Dout * K) return;
    int n = idx / K, k = idx - n * K;
    WT[idx] = f2bf(W[(size_t)k * Dout + n]);
}

// ---------------- aggregation: wave-per-node vectorized gather -------------
// din = VEC*64 bf16 columns. One wave per node; lane handles VEC elements.
template <int VEC> struct VecT;
template <> struct VecT<2> { using T = unsigned int; };
template <> struct VecT<4> { using T = uint2; };
template <> struct VecT<8> { using T = uint4; };

template <int VEC>
__device__ __forceinline__ void vunpack(typename VecT<VEC>::T v, unsigned int* w) {
    if constexpr (VEC == 2) { w[0] = v; }
    else if constexpr (VEC == 4) { w[0] = v.x; w[1] = v.y; }
    else { w[0] = v.x; w[1] = v.y; w[2] = v.z; w[3] = v.w; }
}

template <int VEC>
__global__ __launch_bounds__(256) void aggregate_wave_kernel(
    const ushort_t* __restrict__ h, ushort_t* __restrict__ mean,
    const int* __restrict__ rowptr, const int* __restrict__ csr_src, int nnodes) {
    const int din = VEC * 64;
    int wid = blockIdx.x * 4 + (threadIdx.x >> 6);
    if (wid >= nnodes) return;
    int lane = threadIdx.x & 63;
    int e0 = rowptr[wid], e1 = rowptr[wid + 1];
    const ushort_t* base = h + (size_t)lane * VEC;

    float acc[VEC];
    #pragma unroll
    for (int i = 0; i < VEC; ++i) acc[i] = 0.f;

    using VT = typename VecT<VEC>::T;
    int e = e0;
    for (; e + 2 <= e1; e += 2) {
        int s0 = csr_src[e], s1 = csr_src[e + 1];
        VT v0 = *(const VT*)(base + (size_t)s0 * din);
        VT v1 = *(const VT*)(base + (size_t)s1 * din);
        unsigned int w0[VEC / 2], w1[VEC / 2];
        vunpack<VEC>(v0, w0);
        vunpack<VEC>(v1, w1);
        #pragma unroll
        for (int i = 0; i < VEC / 2; ++i) {
            acc[2 * i + 0] += bf2f((ushort_t)(w0[i] & 0xffffu));
            acc[2 * i + 1] += bf2f((ushort_t)(w0[i] >> 16));
            acc[2 * i + 0] += bf2f((ushort_t)(w1[i] & 0xffffu));
            acc[2 * i + 1] += bf2f((ushort_t)(w1[i] >> 16));
        }
    }
    if (e < e1) {
        int s0 = csr_src[e];
        VT v0 = *(const VT*)(base + (size_t)s0 * din);
        unsigned int w0[VEC / 2];
        vunpack<VEC>(v0, w0);
        #pragma unroll
        for (int i = 0; i < VEC / 2; ++i) {
            acc[2 * i + 0] += bf2f((ushort_t)(w0[i] & 0xffffu));
            acc[2 * i + 1] += bf2f((ushort_t)(w0[i] >> 16));
        }
    }

    int deg = e1 - e0;
    float scale = 1.0f / (float)(deg > 1 ? deg : 1);
    unsigned int o[VEC / 2];
    #pragma unroll
    for (int i = 0; i < VEC / 2; ++i)
        o[i] = (unsigned int)f2bf(acc[2 * i] * scale) |
               ((unsigned int)f2bf(acc[2 * i + 1] * scale) << 16);
    VT ov;
    if constexpr (VEC == 2) { ov = o[0]; }
    else if constexpr (VEC == 4) { ov.x = o[0]; ov.y = o[1]; }
    else { ov.x = o[0]; ov.y = o[1]; ov.z = o[2]; ov.w = o[3]; }
    *(VT*)(mean + (size_t)wid * din + (size_t)lane * VEC) = ov;
}

// ---------------- fused dual-A MFMA GEMM (layer 0) -------------------------
// C = [A1|A2] @ WT^T + bias. 128x128 tile, BK=32.
#define PAD_STRIDE 40
__global__ __launch_bounds__(256) void gemm_mfma_kernel(
    const ushort_t* __restrict__ A1, const ushort_t* __restrict__ A2,
    const ushort_t* __restrict__ WT, const float* __restrict__ bias,
    float* __restrict__ C, int N, int K1, int Dout) {
    __shared__ short As[128 * PAD_STRIDE];
    __shared__ short Bs[128 * PAD_STRIDE];

    const int tid = threadIdx.x;
    const int wave = tid >> 6;
    const int lane = tid & 63;
    const int quad = lane >> 4;
    const int l15 = lane & 15;
    const int rowBase = blockIdx.y * 128;
    const int colBase = blockIdx.x * 128;
    const int wm = (wave >> 1) * 64;
    const int wn = (wave & 1) * 64;

    float4v acc[4][4];
    #pragma unroll
    for (int i = 0; i < 4; ++i)
        #pragma unroll
        for (int j = 0; j < 4; ++j)
            acc[i][j] = (float4v){0.f, 0.f, 0.f, 0.f};

    const int K2 = 2 * K1;
    const int nkt = K2 / 32;
    const int khalf = K1 / 32;
    const int c0 = tid * 2;

    for (int kt = 0; kt < nkt; ++kt) {
        const ushort_t* Asrc;
        int kg;
        if (kt < khalf) { Asrc = A1; kg = kt * 32; }
        else            { Asrc = A2; kg = (kt - khalf) * 32; }
        const int kw = kt * 32;

        float4 a_ld[2], b_ld[2];
        #pragma unroll
        for (int u = 0; u < 2; ++u) {
            int c = c0 + u;
            int r = c >> 2, off = (c & 3) * 8;
            int grow = rowBase + r;
            a_ld[u] = (grow < N) ? *(const float4*)(Asrc + (size_t)grow * K1 + kg + off)
                                 : make_float4(0.f, 0.f, 0.f, 0.f);
            b_ld[u] = *(const float4*)(WT + (size_t)(colBase + r) * K2 + kw + off);
        }
        __syncthreads();
        #pragma unroll
        for (int u = 0; u < 2; ++u) {
            int c = c0 + u;
            int r = c >> 2, off = (c & 3) * 8;
            *(float4*)&As[r * PAD_STRIDE + off] = a_ld[u];
            *(float4*)&Bs[r * PAD_STRIDE + off] = b_ld[u];
        }
        __syncthreads();

        short8 af[4], bf[4];
        #pragma unroll
        for (int i = 0; i < 4; ++i)
            af[i] = *(const short8*)&As[(wm + i * 16 + l15) * PAD_STRIDE + quad * 8];
        #pragma unroll
        for (int j = 0; j < 4; ++j)
            bf[j] = *(const short8*)&Bs[(wn + j * 16 + l15) * PAD_STRIDE + quad * 8];

        #pragma unroll
        for (int i = 0; i < 4; ++i)
            #pragma unroll
            for (int j = 0; j < 4; ++j)
                acc[i][j] = __builtin_amdgcn_mfma_f32_16x16x32_bf16(af[i], bf[j], acc[i][j], 0, 0, 0);
    }

    #pragma unroll
    for (int j = 0; j < 4; ++j) {
        int col = colBase + wn + j * 16 + l15;
        float bv = bias[col];
        #pragma unroll
        for (int i = 0; i < 4; ++i) {
            int rowb = rowBase + wm + i * 16 + quad * 4;
            #pragma unroll
            for (int r = 0; r < 4; ++r) {
                int row = rowb + r;
                if (row < N) C[(size_t)row * Dout + col] = acc[i][j][r] + bv;
            }
        }
    }
}

// ---------------- single-A MFMA GEMM (layers 1/2) --------------------------
// FINAL=false: C_bf16 = A @ WT^T               (projection P = h @ Wl)
// FINAL=true : C_f32  = A @ WT^T + bias + agg  (out = h @ Wr + bl + mean@Wl)
template <bool FINAL>
__global__ __launch_bounds__(256) void gemm1_kernel(
    const ushort_t* __restrict__ A, const ushort_t* __restrict__ WT,
    const float* __restrict__ bias, const ushort_t* __restrict__ aggb,
    float* __restrict__ Cf, ushort_t* __restrict__ Cb,
    int N, int K, int Dout) {
    __shared__ short As[128 * PAD_STRIDE];
    __shared__ short Bs[128 * PAD_STRIDE];

    const int tid = threadIdx.x;
    const int wave = tid >> 6;
    const int lane = tid & 63;
    const int quad = lane >> 4;
    const int l15 = lane & 15;
    const int rowBase = blockIdx.y * 128;
    const int colBase = blockIdx.x * 128;
    const int wm = (wave >> 1) * 64;
    const int wn = (wave & 1) * 64;

    float4v acc[4][4];
    #pragma unroll
    for (int i = 0; i < 4; ++i)
        #pragma unroll
        for (int j = 0; j < 4; ++j)
            acc[i][j] = (float4v){0.f, 0.f, 0.f, 0.f};

    const int nkt = K / 32;
    const int c0 = tid * 2;

    for (int kt = 0; kt < nkt; ++kt) {
        const int k0 = kt * 32;
        float4 a_ld[2], b_ld[2];
        #pragma unroll
        for (int u = 0; u < 2; ++u) {
            int c = c0 + u;
            int r = c >> 2, off = (c & 3) * 8;
            int grow = rowBase + r;
            a_ld[u] = (grow < N) ? *(const float4*)(A + (size_t)grow * K + k0 + off)
                                 : make_float4(0.f, 0.f, 0.f, 0.f);
            b_ld[u] = *(const float4*)(WT + (size_t)(colBase + r) * K + k0 + off);
        }
        __syncthreads();
        #pragma unroll
        for (int u = 0; u < 2; ++u) {
            int c = c0 + u;
            int r = c >> 2, off = (c & 3) * 8;
            *(float4*)&As[r * PAD_STRIDE + off] = a_ld[u];
            *(float4*)&Bs[r * PAD_STRIDE + off] = b_ld[u];
        }
        __syncthreads();

        short8 af[4], bf[4];
        #pragma unroll
        for (int i = 0; i < 4; ++i)
            af[i] = *(const short8*)&As[(wm + i * 16 + l15) * PAD_STRIDE + quad * 8];
        #pragma unroll
        for (int j = 0; j < 4; ++j)
            bf[j] = *(const short8*)&Bs[(wn + j * 16 + l15) * PAD_STRIDE + quad * 8];

        #pragma unroll
        for (int i = 0; i < 4; ++i)
            #pragma unroll
            for (int j = 0; j < 4; ++j)
                acc[i][j] = __builtin_amdgcn_mfma_f32_16x16x32_bf16(af[i], bf[j], acc[i][j], 0, 0, 0);
    }

    #pragma unroll
    for (int j = 0; j < 4; ++j) {
        int col = colBase + wn + j * 16 + l15;
        float bv = FINAL ? bias[col] : 0.f;
        #pragma unroll
        for (int i = 0; i < 4; ++i) {
            int rowb = rowBase + wm + i * 16 + quad * 4;
            #pragma unroll
            for (int r = 0; r < 4; ++r) {
                int row = rowb + r;
                if (row < N) {
                    float v = acc[i][j][r];
                    if (FINAL) {
                        v += bv + bf2f(aggb[(size_t)row * Dout + col]);
                        Cf[(size_t)row * Dout + col] = v;
                    } else {
                        Cb[(size_t)row * Dout + col] = f2bf(v);
                    }
                }
            }
        }
    }
}

// ---------------- BN stats + apply ----------------------------------------
__global__ void colstats_kernel(const float* __restrict__ h, int N, int D,
                                float* __restrict__ sum, float* __restrict__ sumsq) {
    int col = blockIdx.x * 64 + (threadIdx.x & 63);
    int lane = threadIdx.x >> 6;
    float s = 0.f, s2 = 0.f;
    int stride = gridDim.y * 4;
    for (int r = blockIdx.y * 4 + lane; r < N; r += stride) {
        float v = h[(size_t)r * D + col];
        s += v;
        s2 += v * v;
    }
    atomicAdd(&sum[col], s);
    atomicAdd(&sumsq[col], s2);
}

__global__ void bn_relu_bf16_kernel(const float* __restrict__ h, ushort_t* __restrict__ hb,
                                    int N, int D,
                                    const float* __restrict__ sum, const float* __restrict__ sumsq,
                                    const float* __restrict__ g, const float* __restrict__ b) {
    size_t idx = (size_t)blockIdx.x * blockDim.x + threadIdx.x;
    if (idx >= (size_t)N * D) return;
    int col = (int)(idx & (size_t)(D - 1));
    float m = sum[col] / (float)N;
    float var = sumsq[col] / (float)N - m * m;
    float inv = rsqrtf(var + EPS_BN);
    float v = h[idx];
    v = g[col] * (v - m) * inv + b[col];
    hb[idx] = f2bf(v > 0.f ? v : 0.f);
}

__global__ void bn_relu_kernel(float* __restrict__ h, int N, int D,
                               const float* __restrict__ sum, const float* __restrict__ sumsq,
                               const float* __restrict__ g, const float* __restrict__ b) {
    size_t idx = (size_t)blockIdx.x * blockDim.x + threadIdx.x;
    if (idx >= (size_t)N * D) return;
    int col = (int)(idx & (size_t)(D - 1));
    float m = sum[col] / (float)N;
    float var = sumsq[col] / (float)N - m * m;
    float inv = rsqrtf(var + EPS_BN);
    float v = h[idx];
    v = g[col] * (v - m) * inv + b[col];
    h[idx] = v > 0.f ? v : 0.f;
}

// ---------------------------------------------------------------------------
extern "C" void kernel_launch(void* const* d_in, const int* in_sizes, int n_in,
                              void* d_out, int out_size, void* d_ws, size_t ws_size,
                              hipStream_t stream) {
    const float* x     = (const float*)d_in[0];
    const int*   edges = (const int*)d_in[1];
    const float* Wl0 = (const float*)d_in[2];
    const float* bl0 = (const float*)d_in[3];
    const float* Wr0 = (const float*)d_in[4];
    const float* g0  = (const float*)d_in[5];
    const float* b0  = (const float*)d_in[6];
    const float* Wl1 = (const float*)d_in[7];
    const float* bl1 = (const float*)d_in[8];
    const float* Wr1 = (const float*)d_in[9];
    const float* g1  = (const float*)d_in[10];
    const float* b1  = (const float*)d_in[11];
    const float* Wl2 = (const float*)d_in[12];
    const float* bl2 = (const float*)d_in[13];
    const float* Wr2 = (const float*)d_in[14];
    const float* g2  = (const float*)d_in[15];
    const float* b2  = (const float*)d_in[16];

    const int D0 = 128, D1 = 512, D2 = 256, D3 = 128;
    const int n  = in_sizes[0] / D0;   // 50000
    const int ne = in_sizes[1] / 2;    // 800000

    // ---- workspace layout ----
    char* base = (char*)d_ws;
    size_t off = 0;
    auto alloc = [&](size_t bytes) -> char* {
        char* p = base + off;
        off = (off + bytes + 255) & ~(size_t)255;
        return p;
    };
    int*      nzflag  = (int*)alloc(4);
    int*      degi    = (int*)alloc((size_t)n * 4);
    int*      rowptr  = (int*)alloc((size_t)(n + 1) * 4);
    int*      cursor  = (int*)alloc((size_t)n * 4);
    int*      csr_src = (int*)alloc((size_t)ne * 4);
    int*      bsums   = (int*)alloc(64 * 4);
    float*    stats   = (float*)alloc(6 * 512 * 4);
    ushort_t* xb      = (ushort_t*)alloc((size_t)n * D0 * 2);
    ushort_t* mb      = (ushort_t*)alloc((size_t)n * 512 * 2);   // mean / P scratch
    ushort_t* h1b     = (ushort_t*)alloc((size_t)n * D1 * 2);
    ushort_t* h2b     = (ushort_t*)alloc((size_t)n * D2 * 2);
    float*    hf      = (float*)alloc((size_t)n * 512 * 4);      // fp32 GEMM out
    ushort_t* WT0     = (ushort_t*)alloc((size_t)D1 * 2 * D0 * 2);
    ushort_t* WTl1    = (ushort_t*)alloc((size_t)D2 * D1 * 2);
    ushort_t* WTr1    = (ushort_t*)alloc((size_t)D2 * D1 * 2);
    ushort_t* WTl2    = (ushort_t*)alloc((size_t)D3 * D2 * 2);
    ushort_t* WTr2    = (ushort_t*)alloc((size_t)D3 * D2 * 2);
    float*    out     = (float*)d_out;
    // aggP lives in the upper half of hf (idle during each layer's agg phase)
    ushort_t* aggb    = (ushort_t*)(hf + (size_t)n * 256);
    (void)ws_size; (void)n_in; (void)out_size;

    hipMemsetAsync(nzflag, 0, 4, stream);
    hipMemsetAsync(degi, 0, (size_t)n * 4, stream);
    hipMemsetAsync(stats, 0, 6 * 512 * 4, stream);

    // ---- edge format detection + CSR build ----
    detect_fmt_kernel<<<1, 256, 0, stream>>>(edges, nzflag);
    count_deg_kernel<<<(ne + 255) / 256, 256, 0, stream>>>(edges, ne, nzflag, degi);
    int nscan = (n + 1023) / 1024;
    scan1_kernel<<<nscan, 1024, 0, stream>>>(degi, n, rowptr, bsums);
    scan2_kernel<<<1, 64, 0, stream>>>(bsums, nscan, rowptr, n, ne);
    scan3_kernel<<<nscan, 1024, 0, stream>>>(rowptr, n, bsums, cursor);
    scatter_kernel<<<(ne + 255) / 256, 256, 0, stream>>>(edges, ne, nzflag, cursor, csr_src);

    // ---- prep: x -> bf16, weights -> transposed bf16 ----
    f2b_kernel<<<((size_t)n * D0 + 255) / 256, 256, 0, stream>>>(x, xb, n * D0);
    prep_wt_kernel<<<(D1 * 2 * D0 + 255) / 256, 256, 0, stream>>>(Wl0, Wr0, WT0, D0, D1);
    prep_wt1_kernel<<<(D2 * D1 + 255) / 256, 256, 0, stream>>>(Wl1, WTl1, D1, D2);
    prep_wt1_kernel<<<(D2 * D1 + 255) / 256, 256, 0, stream>>>(Wr1, WTr1, D1, D2);
    prep_wt1_kernel<<<(D3 * D2 + 255) / 256, 256, 0, stream>>>(Wl2, WTl2, D2, D3);
    prep_wt1_kernel<<<(D3 * D2 + 255) / 256, 256, 0, stream>>>(Wr2, WTr2, D2, D3);

    const int aggGrid = (n + 3) / 4;

    // ---- layer 0: 128 -> 512 (aggregate-first: din < dout) ----
    aggregate_wave_kernel<2><<<aggGrid, 256, 0, stream>>>(xb, mb, rowptr, csr_src, n);
    gemm_mfma_kernel<<<dim3(D1 / 128, (n + 127) / 128), 256, 0, stream>>>(
        mb, xb, WT0, bl0, hf, n, D0, D1);
    colstats_kernel<<<dim3(D1 / 64, 128), 256, 0, stream>>>(hf, n, D1, stats + 0 * 1024, stats + 0 * 1024 + 512);
    bn_relu_bf16_kernel<<<((size_t)n * D1 + 255) / 256, 256, 0, stream>>>(
        hf, h1b, n, D1, stats + 0 * 1024, stats + 0 * 1024 + 512, g0, b0);

    // ---- layer 1: 512 -> 256 (project-first: dout < din) ----
    gemm1_kernel<false><<<dim3(D2 / 128, (n + 127) / 128), 256, 0, stream>>>(
        h1b, WTl1, nullptr, nullptr, nullptr, mb, n, D1, D2);              // P1 = h1 @ Wl1
    aggregate_wave_kernel<4><<<aggGrid, 256, 0, stream>>>(mb, aggb, rowptr, csr_src, n);
    gemm1_kernel<true><<<dim3(D2 / 128, (n + 127) / 128), 256, 0, stream>>>(
        h1b, WTr1, bl1, aggb, hf, nullptr, n, D1, D2);                     // out = h1@Wr1 + bl1 + agg
    colstats_kernel<<<dim3(D2 / 64, 128), 256, 0, stream>>>(hf, n, D2, stats + 1 * 1024, stats + 1 * 1024 + 512);
    bn_relu_bf16_kernel<<<((size_t)n * D2 + 255) / 256, 256, 0, stream>>>(
        hf, h2b, n, D2, stats + 1 * 1024, stats + 1 * 1024 + 512, g1, b1);

    // ---- layer 2: 256 -> 128 (project-first) ----
    gemm1_kernel<false><<<dim3(D3 / 128, (n + 127) / 128), 256, 0, stream>>>(
        h2b, WTl2, nullptr, nullptr, nullptr, mb, n, D2, D3);              // P2 = h2 @ Wl2
    aggregate_wave_kernel<2><<<aggGrid, 256, 0, stream>>>(mb, aggb, rowptr, csr_src, n);
    gemm1_kernel<true><<<dim3(D3 / 128, (n + 127) / 128), 256, 0, stream>>>(
        h2b, WTr2, bl2, aggb, out, nullptr, n, D2, D3);                    // out = h2@Wr2 + bl2 + agg
    colstats_kernel<<<dim3(D3 / 64, 128), 256, 0, stream>>>(out, n, D3, stats + 2 * 1024, stats + 2 * 1024 + 512);
    bn_relu_kernel<<<((size_t)n * D3 + 255) / 256, 256, 0, stream>>>(
        out, n, D3, stats + 2 * 1024, stats + 2 * 1024 + 512, g2, b2);
}

// Round 4
// 825.645 us; speedup vs baseline: 1.9236x; 1.0702x over previous
//
#include <hip/hip_runtime.h>
#include <cstdint>
#include <cstddef>

// ---------------------------------------------------------------------------
// CellGraphSAGE: 3x (SAGE-mean conv -> BN -> ReLU)
// dims: 128 -> 512 -> 256 -> 128, N=50000 nodes, E=800000 edges
// Round 4:
//  - MFMA operand swap -> transposed C/D fragments -> contiguous float4 /
//    packed-bf16x4 epilogue stores (kills 4x write amplification)
//  - per-layer GEMM pair fused: [P|R] = h @ [Wl|Wr] (A read once, 2x blocks)
//  - aggregate+add fused: out = mean(P[src]) + R + bl in one kernel
// ---------------------------------------------------------------------------

#define EPS_BN 1e-5f

typedef unsigned short ushort_t;
typedef __attribute__((ext_vector_type(8))) short short8;
typedef __attribute__((ext_vector_type(4))) float float4v;

__device__ __forceinline__ float bf2f(ushort_t u) {
    union { unsigned int i; float f; } v; v.i = ((unsigned int)u) << 16; return v.f;
}
__device__ __forceinline__ ushort_t f2bf(float f) {
    union { float f; unsigned int i; } v; v.f = f;
    unsigned int r = v.i + 0x7fffu + ((v.i >> 16) & 1u);  // RNE
    return (ushort_t)(r >> 16);
}

// ---------------- edge format hedge (int64 vs int32 storage) ---------------
__global__ void detect_fmt_kernel(const int* __restrict__ edges, int* __restrict__ nz) {
    int t = threadIdx.x;
    int cnt = 0;
    #pragma unroll
    for (int j = 0; j < 4; ++j) {
        int idx = 2 * (t * 4 + j) + 1;
        if (edges[idx] != 0) cnt++;
    }
    if (cnt) atomicAdd(nz, cnt);
}

__device__ __forceinline__ void edge_sd(const int* __restrict__ p, int e, int ne,
                                        bool is64, int& s, int& d) {
    if (is64) { s = p[2 * e];  d = p[2 * ne + 2 * e]; }
    else      { s = p[e];      d = p[ne + e]; }
}

// ---------------- CSR build ------------------------------------------------
__global__ void count_deg_kernel(const int* __restrict__ edges, int ne,
                                 const int* __restrict__ nz, int* __restrict__ degi) {
    bool is64 = (*nz == 0);
    int e = blockIdx.x * 256 + threadIdx.x;
    if (e < ne) {
        int s, d; edge_sd(edges, e, ne, is64, s, d);
        atomicAdd(&degi[d], 1);
    }
}

__global__ void scan1_kernel(const int* __restrict__ degi, int n,
                             int* __restrict__ rowptr, int* __restrict__ bsums) {
    __shared__ int sh[1024];
    int t = threadIdx.x;
    int i = blockIdx.x * 1024 + t;
    int v = (i < n) ? degi[i] : 0;
    sh[t] = v;
    __syncthreads();
    for (int off = 1; off < 1024; off <<= 1) {
        int x = (t >= off) ? sh[t - off] : 0;
        __syncthreads();
        sh[t] += x;
        __syncthreads();
    }
    if (i < n) rowptr[i] = sh[t] - v;
    if (t == 1023) bsums[blockIdx.x] = sh[t];
}

__global__ void scan2_kernel(int* __restrict__ bsums, int nb,
                             int* __restrict__ rowptr, int n, int total) {
    if (threadIdx.x == 0 && blockIdx.x == 0) {
        int run = 0;
        for (int b = 0; b < nb; ++b) { int t = bsums[b]; bsums[b] = run; run += t; }
        rowptr[n] = total;
    }
}

__global__ void scan3_kernel(int* __restrict__ rowptr, int n,
                             const int* __restrict__ bsums, int* __restrict__ cursor) {
    int i = blockIdx.x * 1024 + threadIdx.x;
    if (i < n) {
        int v = rowptr[i] + bsums[blockIdx.x];
        rowptr[i] = v;
        cursor[i] = v;
    }
}

__global__ void scatter_kernel(const int* __restrict__ edges, int ne,
                               const int* __restrict__ nz,
                               int* __restrict__ cursor, int* __restrict__ csr_src) {
    bool is64 = (*nz == 0);
    int e = blockIdx.x * 256 + threadIdx.x;
    if (e < ne) {
        int s, d; edge_sd(edges, e, ne, is64, s, d);
        int pos = atomicAdd(&cursor[d], 1);
        csr_src[pos] = s;
    }
}

// ---------------- conversions ----------------------------------------------
__global__ void f2b_kernel(const float* __restrict__ in, ushort_t* __restrict__ out, int n) {
    int i = blockIdx.x * 256 + threadIdx.x;
    if (i < n) out[i] = f2bf(in[i]);
}

// dual-source transposed concat along K (layer 0): WT[n][k], k<K1 -> Wl[k][n] else Wr
__global__ void prep_wt_kernel(const float* __restrict__ Wl, const float* __restrict__ Wr,
                               ushort_t* __restrict__ WT, int K1, int Dout) {
    int idx = blockIdx.x * 256 + threadIdx.x;
    int K2 = 2 * K1;
    if (idx >= Dout * K2) return;
    int n = idx / K2, k = idx - n * K2;
    float v = (k < K1) ? Wl[(size_t)k * Dout + n] : Wr[(size_t)(k - K1) * Dout + n];
    WT[idx] = f2bf(v);
}

// dual-source transposed concat along N (layers 1/2): WTc[(2D) x K];
// rows [0,D) = Wl columns, rows [D,2D) = Wr columns.
__global__ void prep_wtc_kernel(const float* __restrict__ Wl, const float* __restrict__ Wr,
                                ushort_t* __restrict__ WTc, int K, int D) {
    int idx = blockIdx.x * 256 + threadIdx.x;
    if (idx >= 2 * D * K) return;
    int nn = idx / K, k = idx - nn * K;
    float v = (nn < D) ? Wl[(size_t)k * D + nn] : Wr[(size_t)k * D + (nn - D)];
    WTc[idx] = f2bf(v);
}

// ---------------- plain aggregation (layer 0): mean of bf16 rows -----------
template <int VEC> struct VecT;
template <> struct VecT<2> { using T = unsigned int; };
template <> struct VecT<4> { using T = uint2; };
template <> struct VecT<8> { using T = uint4; };

template <int VEC>
__device__ __forceinline__ void vunpack(typename VecT<VEC>::T v, unsigned int* w) {
    if constexpr (VEC == 2) { w[0] = v; }
    else if constexpr (VEC == 4) { w[0] = v.x; w[1] = v.y; }
    else { w[0] = v.x; w[1] = v.y; w[2] = v.z; w[3] = v.w; }
}

template <int VEC>
__global__ __launch_bounds__(256) void aggregate_wave_kernel(
    const ushort_t* __restrict__ h, ushort_t* __restrict__ mean,
    const int* __restrict__ rowptr, const int* __restrict__ csr_src, int nnodes) {
    const int din = VEC * 64;
    int wid = blockIdx.x * 4 + (threadIdx.x >> 6);
    if (wid >= nnodes) return;
    int lane = threadIdx.x & 63;
    int e0 = rowptr[wid], e1 = rowptr[wid + 1];
    const ushort_t* base = h + (size_t)lane * VEC;

    float acc[VEC];
    #pragma unroll
    for (int i = 0; i < VEC; ++i) acc[i] = 0.f;

    using VT = typename VecT<VEC>::T;
    int e = e0;
    for (; e + 2 <= e1; e += 2) {
        int s0 = csr_src[e], s1 = csr_src[e + 1];
        VT v0 = *(const VT*)(base + (size_t)s0 * din);
        VT v1 = *(const VT*)(base + (size_t)s1 * din);
        unsigned int w0[VEC / 2], w1[VEC / 2];
        vunpack<VEC>(v0, w0);
        vunpack<VEC>(v1, w1);
        #pragma unroll
        for (int i = 0; i < VEC / 2; ++i) {
            acc[2 * i + 0] += bf2f((ushort_t)(w0[i] & 0xffffu));
            acc[2 * i + 1] += bf2f((ushort_t)(w0[i] >> 16));
            acc[2 * i + 0] += bf2f((ushort_t)(w1[i] & 0xffffu));
            acc[2 * i + 1] += bf2f((ushort_t)(w1[i] >> 16));
        }
    }
    if (e < e1) {
        int s0 = csr_src[e];
        VT v0 = *(const VT*)(base + (size_t)s0 * din);
        unsigned int w0[VEC / 2];
        vunpack<VEC>(v0, w0);
        #pragma unroll
        for (int i = 0; i < VEC / 2; ++i) {
            acc[2 * i + 0] += bf2f((ushort_t)(w0[i] & 0xffffu));
            acc[2 * i + 1] += bf2f((ushort_t)(w0[i] >> 16));
        }
    }

    int deg = e1 - e0;
    float scale = 1.0f / (float)(deg > 1 ? deg : 1);
    unsigned int o[VEC / 2];
    #pragma unroll
    for (int i = 0; i < VEC / 2; ++i)
        o[i] = (unsigned int)f2bf(acc[2 * i] * scale) |
               ((unsigned int)f2bf(acc[2 * i + 1] * scale) << 16);
    VT ov;
    if constexpr (VEC == 2) { ov = o[0]; }
    else if constexpr (VEC == 4) { ov.x = o[0]; ov.y = o[1]; }
    else { ov.x = o[0]; ov.y = o[1]; ov.z = o[2]; ov.w = o[3]; }
    *(VT*)(mean + (size_t)wid * din + (size_t)lane * VEC) = ov;
}

// ---------------- fused aggregate + add (layers 1/2) -----------------------
// PR: N x (2D) bf16, P = cols [0,D), R = cols [D,2D).
// out[node][c] = mean_{src in-nbrs}(P[src][c]) + R[node][c] + bias[c]   (fp32)
template <int VEC>  // VEC = D/64
__global__ __launch_bounds__(256) void aggregate_add_kernel(
    const ushort_t* __restrict__ PR, const float* __restrict__ bias,
    float* __restrict__ outf,
    const int* __restrict__ rowptr, const int* __restrict__ csr_src, int nnodes) {
    const int D = VEC * 64;
    const int stride = 2 * D;
    int wid = blockIdx.x * 4 + (threadIdx.x >> 6);
    if (wid >= nnodes) return;
    int lane = threadIdx.x & 63;
    int e0 = rowptr[wid], e1 = rowptr[wid + 1];
    const ushort_t* base = PR + (size_t)lane * VEC;

    float acc[VEC];
    #pragma unroll
    for (int i = 0; i < VEC; ++i) acc[i] = 0.f;

    using VT = typename VecT<VEC>::T;
    int e = e0;
    for (; e + 2 <= e1; e += 2) {
        int s0 = csr_src[e], s1 = csr_src[e + 1];
        VT v0 = *(const VT*)(base + (size_t)s0 * stride);
        VT v1 = *(const VT*)(base + (size_t)s1 * stride);
        unsigned int w0[VEC / 2], w1[VEC / 2];
        vunpack<VEC>(v0, w0);
        vunpack<VEC>(v1, w1);
        #pragma unroll
        for (int i = 0; i < VEC / 2; ++i) {
            acc[2 * i + 0] += bf2f((ushort_t)(w0[i] & 0xffffu));
            acc[2 * i + 1] += bf2f((ushort_t)(w0[i] >> 16));
            acc[2 * i + 0] += bf2f((ushort_t)(w1[i] & 0xffffu));
            acc[2 * i + 1] += bf2f((ushort_t)(w1[i] >> 16));
        }
    }
    if (e < e1) {
        int s0 = csr_src[e];
        VT v0 = *(const VT*)(base + (size_t)s0 * stride);
        unsigned int w0[VEC / 2];
        vunpack<VEC>(v0, w0);
        #pragma unroll
        for (int i = 0; i < VEC / 2; ++i) {
            acc[2 * i + 0] += bf2f((ushort_t)(w0[i] & 0xffffu));
            acc[2 * i + 1] += bf2f((ushort_t)(w0[i] >> 16));
        }
    }

    int deg = e1 - e0;
    float scale = 1.0f / (float)(deg > 1 ? deg : 1);

    // R half + bias, fp32 out
    VT rv = *(const VT*)(PR + (size_t)wid * stride + D + (size_t)lane * VEC);
    unsigned int rw[VEC / 2];
    vunpack<VEC>(rv, rw);
    float o[VEC];
    #pragma unroll
    for (int i = 0; i < VEC / 2; ++i) {
        o[2 * i + 0] = bf2f((ushort_t)(rw[i] & 0xffffu));
        o[2 * i + 1] = bf2f((ushort_t)(rw[i] >> 16));
    }
    #pragma unroll
    for (int i = 0; i < VEC; ++i)
        o[i] += acc[i] * scale + bias[lane * VEC + i];
    #pragma unroll
    for (int i = 0; i < VEC; ++i)
        outf[(size_t)wid * D + lane * VEC + i] = o[i];
}

// ---------------- fused dual-A MFMA GEMM (layer 0) -------------------------
// C = [A1|A2] @ WT^T + bias (fp32 out). Operand-swapped epilogue: lane holds
// 4 consecutive COLS -> float4 stores.
#define PAD_STRIDE 40
__global__ __launch_bounds__(256) void gemm_dual_kernel(
    const ushort_t* __restrict__ A1, const ushort_t* __restrict__ A2,
    const ushort_t* __restrict__ WT, const float* __restrict__ bias,
    float* __restrict__ C, int N, int K1, int Dout) {
    __shared__ short As[128 * PAD_STRIDE];
    __shared__ short Bs[128 * PAD_STRIDE];

    const int tid = threadIdx.x;
    const int wave = tid >> 6;
    const int lane = tid & 63;
    const int quad = lane >> 4;
    const int l15 = lane & 15;
    const int rowBase = blockIdx.y * 128;
    const int colBase = blockIdx.x * 128;
    const int wm = (wave >> 1) * 64;
    const int wn = (wave & 1) * 64;

    float4v acc[4][4];
    #pragma unroll
    for (int i = 0; i < 4; ++i)
        #pragma unroll
        for (int j = 0; j < 4; ++j)
            acc[i][j] = (float4v){0.f, 0.f, 0.f, 0.f};

    const int K2 = 2 * K1;
    const int nkt = K2 / 32;
    const int khalf = K1 / 32;
    const int c0 = tid * 2;

    for (int kt = 0; kt < nkt; ++kt) {
        const ushort_t* Asrc;
        int kg;
        if (kt < khalf) { Asrc = A1; kg = kt * 32; }
        else            { Asrc = A2; kg = (kt - khalf) * 32; }
        const int kw = kt * 32;

        float4 a_ld[2], b_ld[2];
        #pragma unroll
        for (int u = 0; u < 2; ++u) {
            int c = c0 + u;
            int r = c >> 2, off = (c & 3) * 8;
            int grow = rowBase + r;
            a_ld[u] = (grow < N) ? *(const float4*)(Asrc + (size_t)grow * K1 + kg + off)
                                 : make_float4(0.f, 0.f, 0.f, 0.f);
            b_ld[u] = *(const float4*)(WT + (size_t)(colBase + r) * K2 + kw + off);
        }
        __syncthreads();
        #pragma unroll
        for (int u = 0; u < 2; ++u) {
            int c = c0 + u;
            int r = c >> 2, off = (c & 3) * 8;
            *(float4*)&As[r * PAD_STRIDE + off] = a_ld[u];
            *(float4*)&Bs[r * PAD_STRIDE + off] = b_ld[u];
        }
        __syncthreads();

        short8 af[4], bf[4];
        #pragma unroll
        for (int i = 0; i < 4; ++i)
            af[i] = *(const short8*)&As[(wm + i * 16 + l15) * PAD_STRIDE + quad * 8];
        #pragma unroll
        for (int j = 0; j < 4; ++j)
            bf[j] = *(const short8*)&Bs[(wn + j * 16 + l15) * PAD_STRIDE + quad * 8];

        // operand swap: acc[i][j][r] = C[rowBase+wm+i*16+l15][colBase+wn+j*16+quad*4+r]
        #pragma unroll
        for (int i = 0; i < 4; ++i)
            #pragma unroll
            for (int j = 0; j < 4; ++j)
                acc[i][j] = __builtin_amdgcn_mfma_f32_16x16x32_bf16(bf[j], af[i], acc[i][j], 0, 0, 0);
    }

    #pragma unroll
    for (int i = 0; i < 4; ++i) {
        int row = rowBase + wm + i * 16 + l15;
        if (row >= N) continue;
        #pragma unroll
        for (int j = 0; j < 4; ++j) {
            int colb = colBase + wn + j * 16 + quad * 4;
            float4 bv = *(const float4*)(bias + colb);
            float4 o;
            o.x = acc[i][j][0] + bv.x;
            o.y = acc[i][j][1] + bv.y;
            o.z = acc[i][j][2] + bv.z;
            o.w = acc[i][j][3] + bv.w;
            *(float4*)(C + (size_t)row * Dout + colb) = o;
        }
    }
}

// ---------------- fused PR GEMM (layers 1/2) -------------------------------
// PR = A @ WTc^T  (bf16 out, width 2D). Packed 4xbf16 (8B) stores.
__global__ __launch_bounds__(256) void gemm_pr_kernel(
    const ushort_t* __restrict__ A, const ushort_t* __restrict__ WTc,
    ushort_t* __restrict__ PR, int N, int K, int Wtot) {
    __shared__ short As[128 * PAD_STRIDE];
    __shared__ short Bs[128 * PAD_STRIDE];

    const int tid = threadIdx.x;
    const int wave = tid >> 6;
    const int lane = tid & 63;
    const int quad = lane >> 4;
    const int l15 = lane & 15;
    const int rowBase = blockIdx.y * 128;
    const int colBase = blockIdx.x * 128;
    const int wm = (wave >> 1) * 64;
    const int wn = (wave & 1) * 64;

    float4v acc[4][4];
    #pragma unroll
    for (int i = 0; i < 4; ++i)
        #pragma unroll
        for (int j = 0; j < 4; ++j)
            acc[i][j] = (float4v){0.f, 0.f, 0.f, 0.f};

    const int nkt = K / 32;
    const int c0 = tid * 2;

    for (int kt = 0; kt < nkt; ++kt) {
        const int k0 = kt * 32;
        float4 a_ld[2], b_ld[2];
        #pragma unroll
        for (int u = 0; u < 2; ++u) {
            int c = c0 + u;
            int r = c >> 2, off = (c & 3) * 8;
            int grow = rowBase + r;
            a_ld[u] = (grow < N) ? *(const float4*)(A + (size_t)grow * K + k0 + off)
                                 : make_float4(0.f, 0.f, 0.f, 0.f);
            b_ld[u] = *(const float4*)(WTc + (size_t)(colBase + r) * K + k0 + off);
        }
        __syncthreads();
        #pragma unroll
        for (int u = 0; u < 2; ++u) {
            int c = c0 + u;
            int r = c >> 2, off = (c & 3) * 8;
            *(float4*)&As[r * PAD_STRIDE + off] = a_ld[u];
            *(float4*)&Bs[r * PAD_STRIDE + off] = b_ld[u];
        }
        __syncthreads();

        short8 af[4], bf[4];
        #pragma unroll
        for (int i = 0; i < 4; ++i)
            af[i] = *(const short8*)&As[(wm + i * 16 + l15) * PAD_STRIDE + quad * 8];
        #pragma unroll
        for (int j = 0; j < 4; ++j)
            bf[j] = *(const short8*)&Bs[(wn + j * 16 + l15) * PAD_STRIDE + quad * 8];

        #pragma unroll
        for (int i = 0; i < 4; ++i)
            #pragma unroll
            for (int j = 0; j < 4; ++j)
                acc[i][j] = __builtin_amdgcn_mfma_f32_16x16x32_bf16(bf[j], af[i], acc[i][j], 0, 0, 0);
    }

    #pragma unroll
    for (int i = 0; i < 4; ++i) {
        int row = rowBase + wm + i * 16 + l15;
        if (row >= N) continue;
        #pragma unroll
        for (int j = 0; j < 4; ++j) {
            int colb = colBase + wn + j * 16 + quad * 4;
            uint2 pk;
            pk.x = (unsigned int)f2bf(acc[i][j][0]) | ((unsigned int)f2bf(acc[i][j][1]) << 16);
            pk.y = (unsigned int)f2bf(acc[i][j][2]) | ((unsigned int)f2bf(acc[i][j][3]) << 16);
            *(uint2*)(PR + (size_t)row * Wtot + colb) = pk;
        }
    }
}

// ---------------- BN stats + apply ----------------------------------------
__global__ void colstats_kernel(const float* __restrict__ h, int N, int D,
                                float* __restrict__ sum, float* __restrict__ sumsq) {
    int col = blockIdx.x * 64 + (threadIdx.x & 63);
    int lane = threadIdx.x >> 6;
    float s = 0.f, s2 = 0.f;
    int stride = gridDim.y * 4;
    for (int r = blockIdx.y * 4 + lane; r < N; r += stride) {
        float v = h[(size_t)r * D + col];
        s += v;
        s2 += v * v;
    }
    atomicAdd(&sum[col], s);
    atomicAdd(&sumsq[col], s2);
}

__global__ void bn_relu_bf16_kernel(const float* __restrict__ h, ushort_t* __restrict__ hb,
                                    int N, int D,
                                    const float* __restrict__ sum, const float* __restrict__ sumsq,
                                    const float* __restrict__ g, const float* __restrict__ b) {
    size_t idx = (size_t)blockIdx.x * blockDim.x + threadIdx.x;
    if (idx >= (size_t)N * D) return;
    int col = (int)(idx & (size_t)(D - 1));
    float m = sum[col] / (float)N;
    float var = sumsq[col] / (float)N - m * m;
    float inv = rsqrtf(var + EPS_BN);
    float v = h[idx];
    v = g[col] * (v - m) * inv + b[col];
    hb[idx] = f2bf(v > 0.f ? v : 0.f);
}

__global__ void bn_relu_kernel(float* __restrict__ h, int N, int D,
                               const float* __restrict__ sum, const float* __restrict__ sumsq,
                               const float* __restrict__ g, const float* __restrict__ b) {
    size_t idx = (size_t)blockIdx.x * blockDim.x + threadIdx.x;
    if (idx >= (size_t)N * D) return;
    int col = (int)(idx & (size_t)(D - 1));
    float m = sum[col] / (float)N;
    float var = sumsq[col] / (float)N - m * m;
    float inv = rsqrtf(var + EPS_BN);
    float v = h[idx];
    v = g[col] * (v - m) * inv + b[col];
    h[idx] = v > 0.f ? v : 0.f;
}

// ---------------------------------------------------------------------------
extern "C" void kernel_launch(void* const* d_in, const int* in_sizes, int n_in,
                              void* d_out, int out_size, void* d_ws, size_t ws_size,
                              hipStream_t stream) {
    const float* x     = (const float*)d_in[0];
    const int*   edges = (const int*)d_in[1];
    const float* Wl0 = (const float*)d_in[2];
    const float* bl0 = (const float*)d_in[3];
    const float* Wr0 = (const float*)d_in[4];
    const float* g0  = (const float*)d_in[5];
    const float* b0  = (const float*)d_in[6];
    const float* Wl1 = (const float*)d_in[7];
    const float* bl1 = (const float*)d_in[8];
    const float* Wr1 = (const float*)d_in[9];
    const float* g1  = (const float*)d_in[10];
    const float* b1  = (const float*)d_in[11];
    const float* Wl2 = (const float*)d_in[12];
    const float* bl2 = (const float*)d_in[13];
    const float* Wr2 = (const float*)d_in[14];
    const float* g2  = (const float*)d_in[15];
    const float* b2  = (const float*)d_in[16];

    const int D0 = 128, D1 = 512, D2 = 256, D3 = 128;
    const int n  = in_sizes[0] / D0;   // 50000
    const int ne = in_sizes[1] / 2;    // 800000

    // ---- workspace layout ----
    char* base = (char*)d_ws;
    size_t off = 0;
    auto alloc = [&](size_t bytes) -> char* {
        char* p = base + off;
        off = (off + bytes + 255) & ~(size_t)255;
        return p;
    };
    int*      nzflag  = (int*)alloc(4);
    int*      degi    = (int*)alloc((size_t)n * 4);
    int*      rowptr  = (int*)alloc((size_t)(n + 1) * 4);
    int*      cursor  = (int*)alloc((size_t)n * 4);
    int*      csr_src = (int*)alloc((size_t)ne * 4);
    int*      bsums   = (int*)alloc(64 * 4);
    float*    stats   = (float*)alloc(6 * 512 * 4);
    ushort_t* xb      = (ushort_t*)alloc((size_t)n * D0 * 2);
    ushort_t* mb      = (ushort_t*)alloc((size_t)n * 512 * 2);   // mean(L0) / PR(L1,L2)
    ushort_t* h1b     = (ushort_t*)alloc((size_t)n * D1 * 2);
    ushort_t* h2b     = (ushort_t*)alloc((size_t)n * D2 * 2);
    float*    hf      = (float*)alloc((size_t)n * 512 * 4);      // fp32 pre-BN
    ushort_t* WT0     = (ushort_t*)alloc((size_t)D1 * 2 * D0 * 2);
    ushort_t* WT1c    = (ushort_t*)alloc((size_t)(2 * D2) * D1 * 2);
    ushort_t* WT2c    = (ushort_t*)alloc((size_t)(2 * D3) * D2 * 2);
    float*    out     = (float*)d_out;
    (void)ws_size; (void)n_in; (void)out_size;

    hipMemsetAsync(nzflag, 0, 4, stream);
    hipMemsetAsync(degi, 0, (size_t)n * 4, stream);
    hipMemsetAsync(stats, 0, 6 * 512 * 4, stream);

    // ---- edge format detection + CSR build ----
    detect_fmt_kernel<<<1, 256, 0, stream>>>(edges, nzflag);
    count_deg_kernel<<<(ne + 255) / 256, 256, 0, stream>>>(edges, ne, nzflag, degi);
    int nscan = (n + 1023) / 1024;
    scan1_kernel<<<nscan, 1024, 0, stream>>>(degi, n, rowptr, bsums);
    scan2_kernel<<<1, 64, 0, stream>>>(bsums, nscan, rowptr, n, ne);
    scan3_kernel<<<nscan, 1024, 0, stream>>>(rowptr, n, bsums, cursor);
    scatter_kernel<<<(ne + 255) / 256, 256, 0, stream>>>(edges, ne, nzflag, cursor, csr_src);

    // ---- prep: x -> bf16, weights -> transposed bf16 ----
    f2b_kernel<<<((size_t)n * D0 + 255) / 256, 256, 0, stream>>>(x, xb, n * D0);
    prep_wt_kernel<<<(D1 * 2 * D0 + 255) / 256, 256, 0, stream>>>(Wl0, Wr0, WT0, D0, D1);
    prep_wtc_kernel<<<(2 * D2 * D1 + 255) / 256, 256, 0, stream>>>(Wl1, Wr1, WT1c, D1, D2);
    prep_wtc_kernel<<<(2 * D3 * D2 + 255) / 256, 256, 0, stream>>>(Wl2, Wr2, WT2c, D2, D3);

    const int aggGrid = (n + 3) / 4;

    // ---- layer 0: 128 -> 512 (aggregate-first: din < dout) ----
    aggregate_wave_kernel<2><<<aggGrid, 256, 0, stream>>>(xb, mb, rowptr, csr_src, n);
    gemm_dual_kernel<<<dim3(D1 / 128, (n + 127) / 128), 256, 0, stream>>>(
        mb, xb, WT0, bl0, hf, n, D0, D1);
    colstats_kernel<<<dim3(D1 / 64, 128), 256, 0, stream>>>(hf, n, D1, stats + 0 * 1024, stats + 0 * 1024 + 512);
    bn_relu_bf16_kernel<<<((size_t)n * D1 + 255) / 256, 256, 0, stream>>>(
        hf, h1b, n, D1, stats + 0 * 1024, stats + 0 * 1024 + 512, g0, b0);

    // ---- layer 1: 512 -> 256 (project-first, fused [P|R]) ----
    gemm_pr_kernel<<<dim3(2 * D2 / 128, (n + 127) / 128), 256, 0, stream>>>(
        h1b, WT1c, mb, n, D1, 2 * D2);                              // PR1 = h1 @ [Wl1|Wr1]
    aggregate_add_kernel<4><<<aggGrid, 256, 0, stream>>>(
        mb, bl1, hf, rowptr, csr_src, n);                           // hf = mean(P)+R+bl1
    colstats_kernel<<<dim3(D2 / 64, 128), 256, 0, stream>>>(hf, n, D2, stats + 1 * 1024, stats + 1 * 1024 + 512);
    bn_relu_bf16_kernel<<<((size_t)n * D2 + 255) / 256, 256, 0, stream>>>(
        hf, h2b, n, D2, stats + 1 * 1024, stats + 1 * 1024 + 512, g1, b1);

    // ---- layer 2: 256 -> 128 (project-first, fused [P|R]) ----
    gemm_pr_kernel<<<dim3(2 * D3 / 128, (n + 127) / 128), 256, 0, stream>>>(
        h2b, WT2c, mb, n, D2, 2 * D3);                              // PR2 = h2 @ [Wl2|Wr2]
    aggregate_add_kernel<2><<<aggGrid, 256, 0, stream>>>(
        mb, bl2, out, rowptr, csr_src, n);                          // out = mean(P)+R+bl2
    colstats_kernel<<<dim3(D3 / 64, 128), 256, 0, stream>>>(out, n, D3, stats + 2 * 1024, stats + 2 * 1024 + 512);
    bn_relu_kernel<<<((size_t)n * D3 + 255) / 256, 256, 0, stream>>>(
        out, n, D3, stats + 2 * 1024, stats + 2 * 1024 + 512, g2, b2);
}

// Round 5
// 674.129 us; speedup vs baseline: 2.3560x; 1.2248x over previous
//
#include <hip/hip_runtime.h>
#include <cstdint>
#include <cstddef>

// ---------------------------------------------------------------------------
// CellGraphSAGE: 3x (SAGE-mean conv -> BN -> ReLU)
// dims: 128 -> 512 -> 256 -> 128, N=50000 nodes, E=800000 edges
// Round 5:
//  - GEMM K-loop restaged with __builtin_amdgcn_global_load_lds width=16
//    (m97 structure): unpadded 128x32 LDS tiles, no VGPR round-trip
//  - epilogue restaged through LDS -> full 64B-line stores (kills the 3.7x
//    write amplification seen in rocprof WRITE_SIZE)
//  - aggregation edge loop unrolled x4 (more loads in flight)
// ---------------------------------------------------------------------------

#define EPS_BN 1e-5f

typedef unsigned short ushort_t;
typedef __attribute__((ext_vector_type(8))) short short8;
typedef __attribute__((ext_vector_type(4))) float float4v;

__device__ __forceinline__ float bf2f(ushort_t u) {
    union { unsigned int i; float f; } v; v.i = ((unsigned int)u) << 16; return v.f;
}
__device__ __forceinline__ ushort_t f2bf(float f) {
    union { float f; unsigned int i; } v; v.f = f;
    unsigned int r = v.i + 0x7fffu + ((v.i >> 16) & 1u);  // RNE
    return (ushort_t)(r >> 16);
}

// async 16B global -> LDS (wave-uniform base + lane*16; layout must match)
__device__ __forceinline__ void async_copy16(void* lds, const void* g) {
    __builtin_amdgcn_global_load_lds(
        (const __attribute__((address_space(1))) unsigned int*)g,
        (__attribute__((address_space(3))) unsigned int*)lds, 16, 0, 0);
}

// ---------------- edge format hedge (int64 vs int32 storage) ---------------
__global__ void detect_fmt_kernel(const int* __restrict__ edges, int* __restrict__ nz) {
    int t = threadIdx.x;
    int cnt = 0;
    #pragma unroll
    for (int j = 0; j < 4; ++j) {
        int idx = 2 * (t * 4 + j) + 1;
        if (edges[idx] != 0) cnt++;
    }
    if (cnt) atomicAdd(nz, cnt);
}

__device__ __forceinline__ void edge_sd(const int* __restrict__ p, int e, int ne,
                                        bool is64, int& s, int& d) {
    if (is64) { s = p[2 * e];  d = p[2 * ne + 2 * e]; }
    else      { s = p[e];      d = p[ne + e]; }
}

// ---------------- CSR build ------------------------------------------------
__global__ void count_deg_kernel(const int* __restrict__ edges, int ne,
                                 const int* __restrict__ nz, int* __restrict__ degi) {
    bool is64 = (*nz == 0);
    int e = blockIdx.x * 256 + threadIdx.x;
    if (e < ne) {
        int s, d; edge_sd(edges, e, ne, is64, s, d);
        atomicAdd(&degi[d], 1);
    }
}

__global__ void scan1_kernel(const int* __restrict__ degi, int n,
                             int* __restrict__ rowptr, int* __restrict__ bsums) {
    __shared__ int sh[1024];
    int t = threadIdx.x;
    int i = blockIdx.x * 1024 + t;
    int v = (i < n) ? degi[i] : 0;
    sh[t] = v;
    __syncthreads();
    for (int off = 1; off < 1024; off <<= 1) {
        int x = (t >= off) ? sh[t - off] : 0;
        __syncthreads();
        sh[t] += x;
        __syncthreads();
    }
    if (i < n) rowptr[i] = sh[t] - v;
    if (t == 1023) bsums[blockIdx.x] = sh[t];
}

__global__ void scan2_kernel(int* __restrict__ bsums, int nb,
                             int* __restrict__ rowptr, int n, int total) {
    if (threadIdx.x == 0 && blockIdx.x == 0) {
        int run = 0;
        for (int b = 0; b < nb; ++b) { int t = bsums[b]; bsums[b] = run; run += t; }
        rowptr[n] = total;
    }
}

__global__ void scan3_kernel(int* __restrict__ rowptr, int n,
                             const int* __restrict__ bsums, int* __restrict__ cursor) {
    int i = blockIdx.x * 1024 + threadIdx.x;
    if (i < n) {
        int v = rowptr[i] + bsums[blockIdx.x];
        rowptr[i] = v;
        cursor[i] = v;
    }
}

__global__ void scatter_kernel(const int* __restrict__ edges, int ne,
                               const int* __restrict__ nz,
                               int* __restrict__ cursor, int* __restrict__ csr_src) {
    bool is64 = (*nz == 0);
    int e = blockIdx.x * 256 + threadIdx.x;
    if (e < ne) {
        int s, d; edge_sd(edges, e, ne, is64, s, d);
        int pos = atomicAdd(&cursor[d], 1);
        csr_src[pos] = s;
    }
}

// ---------------- conversions ----------------------------------------------
__global__ void f2b_kernel(const float* __restrict__ in, ushort_t* __restrict__ out, int n) {
    int i = blockIdx.x * 256 + threadIdx.x;
    if (i < n) out[i] = f2bf(in[i]);
}

// dual-source transposed concat along K (layer 0): WT[n][k], k<K1 -> Wl[k][n] else Wr
__global__ void prep_wt_kernel(const float* __restrict__ Wl, const float* __restrict__ Wr,
                               ushort_t* __restrict__ WT, int K1, int Dout) {
    int idx = blockIdx.x * 256 + threadIdx.x;
    int K2 = 2 * K1;
    if (idx >= Dout * K2) return;
    int n = idx / K2, k = idx - n * K2;
    float v = (k < K1) ? Wl[(size_t)k * Dout + n] : Wr[(size_t)(k - K1) * Dout + n];
    WT[idx] = f2bf(v);
}

// dual-source transposed concat along N (layers 1/2): WTc[(2D) x K]
__global__ void prep_wtc_kernel(const float* __restrict__ Wl, const float* __restrict__ Wr,
                                ushort_t* __restrict__ WTc, int K, int D) {
    int idx = blockIdx.x * 256 + threadIdx.x;
    if (idx >= 2 * D * K) return;
    int nn = idx / K, k = idx - nn * K;
    float v = (nn < D) ? Wl[(size_t)k * D + nn] : Wr[(size_t)k * D + (nn - D)];
    WTc[idx] = f2bf(v);
}

// ---------------- aggregation helpers --------------------------------------
template <int VEC> struct VecT;
template <> struct VecT<2> { using T = unsigned int; };
template <> struct VecT<4> { using T = uint2; };
template <> struct VecT<8> { using T = uint4; };

template <int VEC>
__device__ __forceinline__ void vunpack(typename VecT<VEC>::T v, unsigned int* w) {
    if constexpr (VEC == 2) { w[0] = v; }
    else if constexpr (VEC == 4) { w[0] = v.x; w[1] = v.y; }
    else { w[0] = v.x; w[1] = v.y; w[2] = v.z; w[3] = v.w; }
}

template <int VEC>
__device__ __forceinline__ void vaccum(typename VecT<VEC>::T v, float* acc) {
    unsigned int w[VEC / 2];
    vunpack<VEC>(v, w);
    #pragma unroll
    for (int i = 0; i < VEC / 2; ++i) {
        acc[2 * i + 0] += bf2f((ushort_t)(w[i] & 0xffffu));
        acc[2 * i + 1] += bf2f((ushort_t)(w[i] >> 16));
    }
}

// ---------------- plain aggregation (layer 0) ------------------------------
template <int VEC>
__global__ __launch_bounds__(256) void aggregate_wave_kernel(
    const ushort_t* __restrict__ h, ushort_t* __restrict__ mean,
    const int* __restrict__ rowptr, const int* __restrict__ csr_src, int nnodes) {
    const int din = VEC * 64;
    int wid = blockIdx.x * 4 + (threadIdx.x >> 6);
    if (wid >= nnodes) return;
    int lane = threadIdx.x & 63;
    int e0 = rowptr[wid], e1 = rowptr[wid + 1];
    const ushort_t* base = h + (size_t)lane * VEC;

    float acc[VEC];
    #pragma unroll
    for (int i = 0; i < VEC; ++i) acc[i] = 0.f;

    using VT = typename VecT<VEC>::T;
    int e = e0;
    for (; e + 4 <= e1; e += 4) {
        int s0 = csr_src[e], s1 = csr_src[e + 1], s2 = csr_src[e + 2], s3 = csr_src[e + 3];
        VT v0 = *(const VT*)(base + (size_t)s0 * din);
        VT v1 = *(const VT*)(base + (size_t)s1 * din);
        VT v2 = *(const VT*)(base + (size_t)s2 * din);
        VT v3 = *(const VT*)(base + (size_t)s3 * din);
        vaccum<VEC>(v0, acc); vaccum<VEC>(v1, acc);
        vaccum<VEC>(v2, acc); vaccum<VEC>(v3, acc);
    }
    for (; e < e1; ++e) {
        int s = csr_src[e];
        vaccum<VEC>(*(const VT*)(base + (size_t)s * din), acc);
    }

    int deg = e1 - e0;
    float scale = 1.0f / (float)(deg > 1 ? deg : 1);
    unsigned int o[VEC / 2];
    #pragma unroll
    for (int i = 0; i < VEC / 2; ++i)
        o[i] = (unsigned int)f2bf(acc[2 * i] * scale) |
               ((unsigned int)f2bf(acc[2 * i + 1] * scale) << 16);
    VT ov;
    if constexpr (VEC == 2) { ov = o[0]; }
    else if constexpr (VEC == 4) { ov.x = o[0]; ov.y = o[1]; }
    else { ov.x = o[0]; ov.y = o[1]; ov.z = o[2]; ov.w = o[3]; }
    *(VT*)(mean + (size_t)wid * din + (size_t)lane * VEC) = ov;
}

// ---------------- fused aggregate + add (layers 1/2) -----------------------
// PR: N x (2D) bf16, P = cols [0,D), R = cols [D,2D).
// out[node][c] = mean(P[src][c]) + R[node][c] + bias[c]   (fp32)
template <int VEC>  // VEC = D/64
__global__ __launch_bounds__(256) void aggregate_add_kernel(
    const ushort_t* __restrict__ PR, const float* __restrict__ bias,
    float* __restrict__ outf,
    const int* __restrict__ rowptr, const int* __restrict__ csr_src, int nnodes) {
    const int D = VEC * 64;
    const int stride = 2 * D;
    int wid = blockIdx.x * 4 + (threadIdx.x >> 6);
    if (wid >= nnodes) return;
    int lane = threadIdx.x & 63;
    int e0 = rowptr[wid], e1 = rowptr[wid + 1];
    const ushort_t* base = PR + (size_t)lane * VEC;

    float acc[VEC];
    #pragma unroll
    for (int i = 0; i < VEC; ++i) acc[i] = 0.f;

    using VT = typename VecT<VEC>::T;
    int e = e0;
    for (; e + 4 <= e1; e += 4) {
        int s0 = csr_src[e], s1 = csr_src[e + 1], s2 = csr_src[e + 2], s3 = csr_src[e + 3];
        VT v0 = *(const VT*)(base + (size_t)s0 * stride);
        VT v1 = *(const VT*)(base + (size_t)s1 * stride);
        VT v2 = *(const VT*)(base + (size_t)s2 * stride);
        VT v3 = *(const VT*)(base + (size_t)s3 * stride);
        vaccum<VEC>(v0, acc); vaccum<VEC>(v1, acc);
        vaccum<VEC>(v2, acc); vaccum<VEC>(v3, acc);
    }
    for (; e < e1; ++e) {
        int s = csr_src[e];
        vaccum<VEC>(*(const VT*)(base + (size_t)s * stride), acc);
    }

    int deg = e1 - e0;
    float scale = 1.0f / (float)(deg > 1 ? deg : 1);

    VT rv = *(const VT*)(PR + (size_t)wid * stride + D + (size_t)lane * VEC);
    unsigned int rw[VEC / 2];
    vunpack<VEC>(rv, rw);
    float o[VEC];
    #pragma unroll
    for (int i = 0; i < VEC / 2; ++i) {
        o[2 * i + 0] = bf2f((ushort_t)(rw[i] & 0xffffu));
        o[2 * i + 1] = bf2f((ushort_t)(rw[i] >> 16));
    }
    #pragma unroll
    for (int i = 0; i < VEC; ++i)
        o[i] += acc[i] * scale + bias[lane * VEC + i];
    #pragma unroll
    for (int i = 0; i < VEC; ++i)
        outf[(size_t)wid * D + lane * VEC + i] = o[i];
}

// ---------------- MFMA GEMM with global_load_lds staging -------------------
// DUAL:  C = [A1|A2] @ BT^T (+bias, fp32 out)    [layer 0]
// !DUAL: C = A1 @ BT^T (bf16 out, no bias)       [layers 1/2 PR]
// 128x128 tile per block (4 waves x 64x64), BK=32, unpadded LDS 128x32.
template <bool DUAL, bool BF16OUT>
__global__ __launch_bounds__(256) void gemm_glds_kernel(
    const ushort_t* __restrict__ A1, const ushort_t* __restrict__ A2,
    const ushort_t* __restrict__ BT, const float* __restrict__ bias,
    float* __restrict__ Cf, ushort_t* __restrict__ Cb,
    int N, int K1, int Ktot, int Wtot) {
    __shared__ ushort_t As[128 * 32];  // 8 KB
    __shared__ ushort_t Bs[128 * 32];  // 8 KB

    const int tid = threadIdx.x;
    const int wave = tid >> 6;
    const int lane = tid & 63;
    const int quad = lane >> 4;
    const int l15 = lane & 15;
    const int rowBase = blockIdx.y * 128;
    const int colBase = blockIdx.x * 128;
    const int wm = (wave >> 1) * 64;
    const int wn = (wave & 1) * 64;

    float4v acc[4][4];
    #pragma unroll
    for (int i = 0; i < 4; ++i)
        #pragma unroll
        for (int j = 0; j < 4; ++j)
            acc[i][j] = (float4v){0.f, 0.f, 0.f, 0.f};

    const int nkt = Ktot / 32;
    const int khalf = K1 / 32;

    for (int kt = 0; kt < nkt; ++kt) {
        const ushort_t* Asrc = A1;
        int kg = kt * 32;
        if (DUAL && kt >= khalf) { Asrc = A2; kg = (kt - khalf) * 32; }
        const int kb = kt * 32;

        // async DMA: chunk c = u*256 + tid; LDS dest = base + lane*16 (uniform base)
        #pragma unroll
        for (int u = 0; u < 2; ++u) {
            int c = u * 256 + tid;
            int r = c >> 2, off = (c & 3) * 8;
            int grow = rowBase + r;
            if (grow >= N) grow = N - 1;  // clamp (stores are row-guarded)
            async_copy16(&As[c * 8], Asrc + (size_t)grow * K1 + kg + off);
            async_copy16(&Bs[c * 8], BT + (size_t)(colBase + r) * Ktot + kb + off);
        }
        __syncthreads();  // drains vmcnt -> LDS tiles ready

        short8 af[4], bf4[4];
        #pragma unroll
        for (int i = 0; i < 4; ++i)
            af[i] = *(const short8*)&As[(wm + i * 16 + l15) * 32 + quad * 8];
        #pragma unroll
        for (int j = 0; j < 4; ++j)
            bf4[j] = *(const short8*)&Bs[(wn + j * 16 + l15) * 32 + quad * 8];

        // operand swap: acc[i][j][r] = C[wm+i*16+l15][wn+j*16+quad*4+r]
        #pragma unroll
        for (int i = 0; i < 4; ++i)
            #pragma unroll
            for (int j = 0; j < 4; ++j)
                acc[i][j] = __builtin_amdgcn_mfma_f32_16x16x32_bf16(bf4[j], af[i], acc[i][j], 0, 0, 0);
        __syncthreads();  // all reads done before next DMA overwrites
    }

    // ---- epilogue: restage via per-wave 4KB LDS region -> full-line stores
    if (BF16OUT) {
        ushort_t* lws = (wave < 2) ? &As[wave * 2048] : &Bs[(wave - 2) * 2048];
        #pragma unroll
        for (int p = 0; p < 2; ++p) {
            #pragma unroll
            for (int jj = 0; jj < 2; ++jj) {
                int j = 2 * p + jj;
                #pragma unroll
                for (int i = 0; i < 4; ++i) {
                    uint2 pk;
                    pk.x = (unsigned int)f2bf(acc[i][j][0]) | ((unsigned int)f2bf(acc[i][j][1]) << 16);
                    pk.y = (unsigned int)f2bf(acc[i][j][2]) | ((unsigned int)f2bf(acc[i][j][3]) << 16);
                    *(uint2*)&lws[(i * 16 + l15) * 32 + jj * 16 + quad * 4] = pk;
                }
            }
            __syncthreads();
            #pragma unroll
            for (int it = 0; it < 4; ++it) {
                int c = it * 64 + lane;
                int row = c >> 2, coff = (c & 3) * 8;
                int grow = rowBase + wm + row;
                if (grow < N) {
                    uint4 v = *(const uint4*)&lws[row * 32 + coff];
                    *(uint4*)(Cb + (size_t)grow * Wtot + colBase + wn + p * 32 + coff) = v;
                }
            }
            __syncthreads();
        }
    } else {
        float* lwf = (float*)((wave < 2) ? (void*)&As[wave * 2048] : (void*)&Bs[(wave - 2) * 2048]);
        #pragma unroll
        for (int j = 0; j < 4; ++j) {
            int colb = colBase + wn + j * 16 + quad * 4;
            float4 bv = *(const float4*)(bias + colb);
            #pragma unroll
            for (int i = 0; i < 4; ++i) {
                float4 o;
                o.x = acc[i][j][0] + bv.x;
                o.y = acc[i][j][1] + bv.y;
                o.z = acc[i][j][2] + bv.z;
                o.w = acc[i][j][3] + bv.w;
                *(float4*)&lwf[(i * 16 + l15) * 16 + quad * 4] = o;
            }
            __syncthreads();
            #pragma unroll
            for (int it = 0; it < 4; ++it) {
                int c = it * 64 + lane;
                int row = c >> 2, coff = (c & 3) * 4;
                int grow = rowBase + wm + row;
                if (grow < N)
                    *(float4*)(Cf + (size_t)grow * Wtot + colBase + wn + j * 16 + coff) =
                        *(const float4*)&lwf[row * 16 + coff];
            }
            __syncthreads();
        }
    }
}

// ---------------- BN stats + apply ----------------------------------------
__global__ void colstats_kernel(const float* __restrict__ h, int N, int D,
                                float* __restrict__ sum, float* __restrict__ sumsq) {
    int col = blockIdx.x * 64 + (threadIdx.x & 63);
    int lane = threadIdx.x >> 6;
    float s = 0.f, s2 = 0.f;
    int stride = gridDim.y * 4;
    for (int r = blockIdx.y * 4 + lane; r < N; r += stride) {
        float v = h[(size_t)r * D + col];
        s += v;
        s2 += v * v;
    }
    atomicAdd(&sum[col], s);
    atomicAdd(&sumsq[col], s2);
}

__global__ void bn_relu_bf16_kernel(const float* __restrict__ h, ushort_t* __restrict__ hb,
                                    int N, int D,
                                    const float* __restrict__ sum, const float* __restrict__ sumsq,
                                    const float* __restrict__ g, const float* __restrict__ b) {
    size_t idx = (size_t)blockIdx.x * blockDim.x + threadIdx.x;
    if (idx >= (size_t)N * D) return;
    int col = (int)(idx & (size_t)(D - 1));
    float m = sum[col] / (float)N;
    float var = sumsq[col] / (float)N - m * m;
    float inv = rsqrtf(var + EPS_BN);
    float v = h[idx];
    v = g[col] * (v - m) * inv + b[col];
    hb[idx] = f2bf(v > 0.f ? v : 0.f);
}

__global__ void bn_relu_kernel(float* __restrict__ h, int N, int D,
                               const float* __restrict__ sum, const float* __restrict__ sumsq,
                               const float* __restrict__ g, const float* __restrict__ b) {
    size_t idx = (size_t)blockIdx.x * blockDim.x + threadIdx.x;
    if (idx >= (size_t)N * D) return;
    int col = (int)(idx & (size_t)(D - 1));
    float m = sum[col] / (float)N;
    float var = sumsq[col] / (float)N - m * m;
    float inv = rsqrtf(var + EPS_BN);
    float v = h[idx];
    v = g[col] * (v - m) * inv + b[col];
    h[idx] = v > 0.f ? v : 0.f;
}

// ---------------------------------------------------------------------------
extern "C" void kernel_launch(void* const* d_in, const int* in_sizes, int n_in,
                              void* d_out, int out_size, void* d_ws, size_t ws_size,
                              hipStream_t stream) {
    const float* x     = (const float*)d_in[0];
    const int*   edges = (const int*)d_in[1];
    const float* Wl0 = (const float*)d_in[2];
    const float* bl0 = (const float*)d_in[3];
    const float* Wr0 = (const float*)d_in[4];
    const float* g0  = (const float*)d_in[5];
    const float* b0  = (const float*)d_in[6];
    const float* Wl1 = (const float*)d_in[7];
    const float* bl1 = (const float*)d_in[8];
    const float* Wr1 = (const float*)d_in[9];
    const float* g1  = (const float*)d_in[10];
    const float* b1  = (const float*)d_in[11];
    const float* Wl2 = (const float*)d_in[12];
    const float* bl2 = (const float*)d_in[13];
    const float* Wr2 = (const float*)d_in[14];
    const float* g2  = (const float*)d_in[15];
    const float* b2  = (const float*)d_in[16];

    const int D0 = 128, D1 = 512, D2 = 256, D3 = 128;
    const int n  = in_sizes[0] / D0;   // 50000
    const int ne = in_sizes[1] / 2;    // 800000

    // ---- workspace layout ----
    char* base = (char*)d_ws;
    size_t off = 0;
    auto alloc = [&](size_t bytes) -> char* {
        char* p = base + off;
        off = (off + bytes + 255) & ~(size_t)255;
        return p;
    };
    int*      nzflag  = (int*)alloc(4);
    int*      degi    = (int*)alloc((size_t)n * 4);
    int*      rowptr  = (int*)alloc((size_t)(n + 1) * 4);
    int*      cursor  = (int*)alloc((size_t)n * 4);
    int*      csr_src = (int*)alloc((size_t)ne * 4);
    int*      bsums   = (int*)alloc(64 * 4);
    float*    stats   = (float*)alloc(6 * 512 * 4);
    ushort_t* xb      = (ushort_t*)alloc((size_t)n * D0 * 2);
    ushort_t* mb      = (ushort_t*)alloc((size_t)n * 512 * 2);   // mean(L0) / PR(L1,L2)
    ushort_t* h1b     = (ushort_t*)alloc((size_t)n * D1 * 2);
    ushort_t* h2b     = (ushort_t*)alloc((size_t)n * D2 * 2);
    float*    hf      = (float*)alloc((size_t)n * 512 * 4);      // fp32 pre-BN
    ushort_t* WT0     = (ushort_t*)alloc((size_t)D1 * 2 * D0 * 2);
    ushort_t* WT1c    = (ushort_t*)alloc((size_t)(2 * D2) * D1 * 2);
    ushort_t* WT2c    = (ushort_t*)alloc((size_t)(2 * D3) * D2 * 2);
    float*    out     = (float*)d_out;
    (void)ws_size; (void)n_in; (void)out_size;

    hipMemsetAsync(nzflag, 0, 4, stream);
    hipMemsetAsync(degi, 0, (size_t)n * 4, stream);
    hipMemsetAsync(stats, 0, 6 * 512 * 4, stream);

    // ---- edge format detection + CSR build ----
    detect_fmt_kernel<<<1, 256, 0, stream>>>(edges, nzflag);
    count_deg_kernel<<<(ne + 255) / 256, 256, 0, stream>>>(edges, ne, nzflag, degi);
    int nscan = (n + 1023) / 1024;
    scan1_kernel<<<nscan, 1024, 0, stream>>>(degi, n, rowptr, bsums);
    scan2_kernel<<<1, 64, 0, stream>>>(bsums, nscan, rowptr, n, ne);
    scan3_kernel<<<nscan, 1024, 0, stream>>>(rowptr, n, bsums, cursor);
    scatter_kernel<<<(ne + 255) / 256, 256, 0, stream>>>(edges, ne, nzflag, cursor, csr_src);

    // ---- prep: x -> bf16, weights -> transposed bf16 ----
    f2b_kernel<<<((size_t)n * D0 + 255) / 256, 256, 0, stream>>>(x, xb, n * D0);
    prep_wt_kernel<<<(D1 * 2 * D0 + 255) / 256, 256, 0, stream>>>(Wl0, Wr0, WT0, D0, D1);
    prep_wtc_kernel<<<(2 * D2 * D1 + 255) / 256, 256, 0, stream>>>(Wl1, Wr1, WT1c, D1, D2);
    prep_wtc_kernel<<<(2 * D3 * D2 + 255) / 256, 256, 0, stream>>>(Wl2, Wr2, WT2c, D2, D3);

    const int aggGrid = (n + 3) / 4;
    const int rowBlocks = (n + 127) / 128;

    // ---- layer 0: 128 -> 512 (aggregate-first: din < dout) ----
    aggregate_wave_kernel<2><<<aggGrid, 256, 0, stream>>>(xb, mb, rowptr, csr_src, n);
    gemm_glds_kernel<true, false><<<dim3(D1 / 128, rowBlocks), 256, 0, stream>>>(
        mb, xb, WT0, bl0, hf, nullptr, n, D0, 2 * D0, D1);
    colstats_kernel<<<dim3(D1 / 64, 128), 256, 0, stream>>>(hf, n, D1, stats + 0 * 1024, stats + 0 * 1024 + 512);
    bn_relu_bf16_kernel<<<((size_t)n * D1 + 255) / 256, 256, 0, stream>>>(
        hf, h1b, n, D1, stats + 0 * 1024, stats + 0 * 1024 + 512, g0, b0);

    // ---- layer 1: 512 -> 256 (project-first, fused [P|R]) ----
    gemm_glds_kernel<false, true><<<dim3(2 * D2 / 128, rowBlocks), 256, 0, stream>>>(
        h1b, nullptr, WT1c, nullptr, nullptr, mb, n, D1, D1, 2 * D2);   // PR1 = h1 @ [Wl1|Wr1]
    aggregate_add_kernel<4><<<aggGrid, 256, 0, stream>>>(
        mb, bl1, hf, rowptr, csr_src, n);                                // hf = mean(P)+R+bl1
    colstats_kernel<<<dim3(D2 / 64, 128), 256, 0, stream>>>(hf, n, D2, stats + 1 * 1024, stats + 1 * 1024 + 512);
    bn_relu_bf16_kernel<<<((size_t)n * D2 + 255) / 256, 256, 0, stream>>>(
        hf, h2b, n, D2, stats + 1 * 1024, stats + 1 * 1024 + 512, g1, b1);

    // ---- layer 2: 256 -> 128 (project-first, fused [P|R]) ----
    gemm_glds_kernel<false, true><<<dim3(2 * D3 / 128, rowBlocks), 256, 0, stream>>>(
        h2b, nullptr, WT2c, nullptr, nullptr, mb, n, D2, D2, 2 * D3);   // PR2 = h2 @ [Wl2|Wr2]
    aggregate_add_kernel<2><<<aggGrid, 256, 0, stream>>>(
        mb, bl2, out, rowptr, csr_src, n);                               // out = mean(P)+R+bl2
    colstats_kernel<<<dim3(D3 / 64, 128), 256, 0, stream>>>(out, n, D3, stats + 2 * 1024, stats + 2 * 1024 + 512);
    bn_relu_kernel<<<((size_t)n * D3 + 255) / 256, 256, 0, stream>>>(
        out, n, D3, stats + 2 * 1024, stats + 2 * 1024 + 512, g2, b2);
}

// Round 6
// 665.107 us; speedup vs baseline: 2.3879x; 1.0136x over previous
//
#include <hip/hip_runtime.h>
#include <cstdint>
#include <cstddef>

// ---------------------------------------------------------------------------
// CellGraphSAGE: 3x (SAGE-mean conv -> BN -> ReLU)
// dims: 128 -> 512 -> 256 -> 128, N=50000 nodes, E=800000 edges
// Round 6:
//  - entire pre-BN pipeline in bf16: GEMM/aggregate emit bf16 pre-BN,
//    colstats + bn_relu read bf16 (halves ~270 MB of fp32 streaming)
//  - aggregation gather loop unrolled x8 (latency-bound, VGPRs cheap)
//  - aggregate_add writes packed bf16 (halves its write traffic)
// ---------------------------------------------------------------------------

#define EPS_BN 1e-5f

typedef unsigned short ushort_t;
typedef __attribute__((ext_vector_type(8))) short short8;
typedef __attribute__((ext_vector_type(4))) float float4v;

__device__ __forceinline__ float bf2f(ushort_t u) {
    union { unsigned int i; float f; } v; v.i = ((unsigned int)u) << 16; return v.f;
}
__device__ __forceinline__ ushort_t f2bf(float f) {
    union { float f; unsigned int i; } v; v.f = f;
    unsigned int r = v.i + 0x7fffu + ((v.i >> 16) & 1u);  // RNE
    return (ushort_t)(r >> 16);
}

// async 16B global -> LDS (wave-uniform base + lane*16)
__device__ __forceinline__ void async_copy16(void* lds, const void* g) {
    __builtin_amdgcn_global_load_lds(
        (const __attribute__((address_space(1))) unsigned int*)g,
        (__attribute__((address_space(3))) unsigned int*)lds, 16, 0, 0);
}

// ---------------- edge format hedge (int64 vs int32 storage) ---------------
__global__ void detect_fmt_kernel(const int* __restrict__ edges, int* __restrict__ nz) {
    int t = threadIdx.x;
    int cnt = 0;
    #pragma unroll
    for (int j = 0; j < 4; ++j) {
        int idx = 2 * (t * 4 + j) + 1;
        if (edges[idx] != 0) cnt++;
    }
    if (cnt) atomicAdd(nz, cnt);
}

__device__ __forceinline__ void edge_sd(const int* __restrict__ p, int e, int ne,
                                        bool is64, int& s, int& d) {
    if (is64) { s = p[2 * e];  d = p[2 * ne + 2 * e]; }
    else      { s = p[e];      d = p[ne + e]; }
}

// ---------------- CSR build ------------------------------------------------
__global__ void count_deg_kernel(const int* __restrict__ edges, int ne,
                                 const int* __restrict__ nz, int* __restrict__ degi) {
    bool is64 = (*nz == 0);
    int e = blockIdx.x * 256 + threadIdx.x;
    if (e < ne) {
        int s, d; edge_sd(edges, e, ne, is64, s, d);
        atomicAdd(&degi[d], 1);
    }
}

__global__ void scan1_kernel(const int* __restrict__ degi, int n,
                             int* __restrict__ rowptr, int* __restrict__ bsums) {
    __shared__ int sh[1024];
    int t = threadIdx.x;
    int i = blockIdx.x * 1024 + t;
    int v = (i < n) ? degi[i] : 0;
    sh[t] = v;
    __syncthreads();
    for (int off = 1; off < 1024; off <<= 1) {
        int x = (t >= off) ? sh[t - off] : 0;
        __syncthreads();
        sh[t] += x;
        __syncthreads();
    }
    if (i < n) rowptr[i] = sh[t] - v;
    if (t == 1023) bsums[blockIdx.x] = sh[t];
}

__global__ void scan2_kernel(int* __restrict__ bsums, int nb,
                             int* __restrict__ rowptr, int n, int total) {
    if (threadIdx.x == 0 && blockIdx.x == 0) {
        int run = 0;
        for (int b = 0; b < nb; ++b) { int t = bsums[b]; bsums[b] = run; run += t; }
        rowptr[n] = total;
    }
}

__global__ void scan3_kernel(int* __restrict__ rowptr, int n,
                             const int* __restrict__ bsums, int* __restrict__ cursor) {
    int i = blockIdx.x * 1024 + threadIdx.x;
    if (i < n) {
        int v = rowptr[i] + bsums[blockIdx.x];
        rowptr[i] = v;
        cursor[i] = v;
    }
}

__global__ void scatter_kernel(const int* __restrict__ edges, int ne,
                               const int* __restrict__ nz,
                               int* __restrict__ cursor, int* __restrict__ csr_src) {
    bool is64 = (*nz == 0);
    int e = blockIdx.x * 256 + threadIdx.x;
    if (e < ne) {
        int s, d; edge_sd(edges, e, ne, is64, s, d);
        int pos = atomicAdd(&cursor[d], 1);
        csr_src[pos] = s;
    }
}

// ---------------- conversions ----------------------------------------------
__global__ void f2b_kernel(const float* __restrict__ in, ushort_t* __restrict__ out, int n) {
    int i = blockIdx.x * 256 + threadIdx.x;
    if (i < n) out[i] = f2bf(in[i]);
}

// dual-source transposed concat along K (layer 0)
__global__ void prep_wt_kernel(const float* __restrict__ Wl, const float* __restrict__ Wr,
                               ushort_t* __restrict__ WT, int K1, int Dout) {
    int idx = blockIdx.x * 256 + threadIdx.x;
    int K2 = 2 * K1;
    if (idx >= Dout * K2) return;
    int n = idx / K2, k = idx - n * K2;
    float v = (k < K1) ? Wl[(size_t)k * Dout + n] : Wr[(size_t)(k - K1) * Dout + n];
    WT[idx] = f2bf(v);
}

// dual-source transposed concat along N (layers 1/2): WTc[(2D) x K]
__global__ void prep_wtc_kernel(const float* __restrict__ Wl, const float* __restrict__ Wr,
                                ushort_t* __restrict__ WTc, int K, int D) {
    int idx = blockIdx.x * 256 + threadIdx.x;
    if (idx >= 2 * D * K) return;
    int nn = idx / K, k = idx - nn * K;
    float v = (nn < D) ? Wl[(size_t)k * D + nn] : Wr[(size_t)k * D + (nn - D)];
    WTc[idx] = f2bf(v);
}

// ---------------- aggregation helpers --------------------------------------
template <int VEC> struct VecT;
template <> struct VecT<2> { using T = unsigned int; };
template <> struct VecT<4> { using T = uint2; };
template <> struct VecT<8> { using T = uint4; };

template <int VEC>
__device__ __forceinline__ void vunpack(typename VecT<VEC>::T v, unsigned int* w) {
    if constexpr (VEC == 2) { w[0] = v; }
    else if constexpr (VEC == 4) { w[0] = v.x; w[1] = v.y; }
    else { w[0] = v.x; w[1] = v.y; w[2] = v.z; w[3] = v.w; }
}

template <int VEC>
__device__ __forceinline__ void vaccum(typename VecT<VEC>::T v, float* acc) {
    unsigned int w[VEC / 2];
    vunpack<VEC>(v, w);
    #pragma unroll
    for (int i = 0; i < VEC / 2; ++i) {
        acc[2 * i + 0] += bf2f((ushort_t)(w[i] & 0xffffu));
        acc[2 * i + 1] += bf2f((ushort_t)(w[i] >> 16));
    }
}

// gather loop, unrolled x8 with cascade tail; rows at stride `rstride` shorts
template <int VEC>
__device__ __forceinline__ void gather_sum(
    const ushort_t* __restrict__ base, const int* __restrict__ csr_src,
    int e0, int e1, int rstride, float* acc) {
    using VT = typename VecT<VEC>::T;
    int e = e0;
    for (; e + 8 <= e1; e += 8) {
        VT v[8];
        #pragma unroll
        for (int u = 0; u < 8; ++u)
            v[u] = *(const VT*)(base + (size_t)csr_src[e + u] * rstride);
        #pragma unroll
        for (int u = 0; u < 8; ++u) vaccum<VEC>(v[u], acc);
    }
    if (e + 4 <= e1) {
        VT v[4];
        #pragma unroll
        for (int u = 0; u < 4; ++u)
            v[u] = *(const VT*)(base + (size_t)csr_src[e + u] * rstride);
        #pragma unroll
        for (int u = 0; u < 4; ++u) vaccum<VEC>(v[u], acc);
        e += 4;
    }
    if (e + 2 <= e1) {
        VT v0 = *(const VT*)(base + (size_t)csr_src[e] * rstride);
        VT v1 = *(const VT*)(base + (size_t)csr_src[e + 1] * rstride);
        vaccum<VEC>(v0, acc); vaccum<VEC>(v1, acc);
        e += 2;
    }
    if (e < e1)
        vaccum<VEC>(*(const VT*)(base + (size_t)csr_src[e] * rstride), acc);
}

// ---------------- plain aggregation (layer 0): bf16 mean -------------------
template <int VEC>
__global__ __launch_bounds__(256) void aggregate_wave_kernel(
    const ushort_t* __restrict__ h, ushort_t* __restrict__ mean,
    const int* __restrict__ rowptr, const int* __restrict__ csr_src, int nnodes) {
    const int din = VEC * 64;
    int wid = blockIdx.x * 4 + (threadIdx.x >> 6);
    if (wid >= nnodes) return;
    int lane = threadIdx.x & 63;
    int e0 = rowptr[wid], e1 = rowptr[wid + 1];

    float acc[VEC];
    #pragma unroll
    for (int i = 0; i < VEC; ++i) acc[i] = 0.f;
    gather_sum<VEC>(h + (size_t)lane * VEC, csr_src, e0, e1, din, acc);

    int deg = e1 - e0;
    float scale = 1.0f / (float)(deg > 1 ? deg : 1);
    unsigned int o[VEC / 2];
    #pragma unroll
    for (int i = 0; i < VEC / 2; ++i)
        o[i] = (unsigned int)f2bf(acc[2 * i] * scale) |
               ((unsigned int)f2bf(acc[2 * i + 1] * scale) << 16);
    using VT = typename VecT<VEC>::T;
    VT ov;
    if constexpr (VEC == 2) { ov = o[0]; }
    else if constexpr (VEC == 4) { ov.x = o[0]; ov.y = o[1]; }
    else { ov.x = o[0]; ov.y = o[1]; ov.z = o[2]; ov.w = o[3]; }
    *(VT*)(mean + (size_t)wid * din + (size_t)lane * VEC) = ov;
}

// ---------------- fused aggregate + add, bf16 out (layers 1/2) -------------
// PR: N x (2D) bf16. pre[node][c] = mean(P[src][c]) + R[node][c] + bias[c]
template <int VEC>  // VEC = D/64
__global__ __launch_bounds__(256) void aggregate_add_kernel(
    const ushort_t* __restrict__ PR, const float* __restrict__ bias,
    ushort_t* __restrict__ pre,
    const int* __restrict__ rowptr, const int* __restrict__ csr_src, int nnodes) {
    const int D = VEC * 64;
    const int stride = 2 * D;
    int wid = blockIdx.x * 4 + (threadIdx.x >> 6);
    if (wid >= nnodes) return;
    int lane = threadIdx.x & 63;
    int e0 = rowptr[wid], e1 = rowptr[wid + 1];

    float acc[VEC];
    #pragma unroll
    for (int i = 0; i < VEC; ++i) acc[i] = 0.f;
    gather_sum<VEC>(PR + (size_t)lane * VEC, csr_src, e0, e1, stride, acc);

    int deg = e1 - e0;
    float scale = 1.0f / (float)(deg > 1 ? deg : 1);

    using VT = typename VecT<VEC>::T;
    VT rv = *(const VT*)(PR + (size_t)wid * stride + D + (size_t)lane * VEC);
    unsigned int rw[VEC / 2];
    vunpack<VEC>(rv, rw);
    float o[VEC];
    #pragma unroll
    for (int i = 0; i < VEC / 2; ++i) {
        o[2 * i + 0] = bf2f((ushort_t)(rw[i] & 0xffffu));
        o[2 * i + 1] = bf2f((ushort_t)(rw[i] >> 16));
    }
    #pragma unroll
    for (int i = 0; i < VEC; ++i)
        o[i] += acc[i] * scale + bias[lane * VEC + i];

    unsigned int ow[VEC / 2];
    #pragma unroll
    for (int i = 0; i < VEC / 2; ++i)
        ow[i] = (unsigned int)f2bf(o[2 * i]) | ((unsigned int)f2bf(o[2 * i + 1]) << 16);
    VT ov;
    if constexpr (VEC == 2) { ov = ow[0]; }
    else if constexpr (VEC == 4) { ov.x = ow[0]; ov.y = ow[1]; }
    else { ov.x = ow[0]; ov.y = ow[1]; ov.z = ow[2]; ov.w = ow[3]; }
    *(VT*)(pre + (size_t)wid * D + (size_t)lane * VEC) = ov;
}

// ---------------- MFMA GEMM with global_load_lds staging -------------------
// DUAL: C = [A1|A2] @ BT^T ; BIAS adds bias[col]; bf16 out via LDS restage.
template <bool DUAL, bool BIAS>
__global__ __launch_bounds__(256) void gemm_glds_kernel(
    const ushort_t* __restrict__ A1, const ushort_t* __restrict__ A2,
    const ushort_t* __restrict__ BT, const float* __restrict__ bias,
    ushort_t* __restrict__ Cb, int N, int K1, int Ktot, int Wtot) {
    __shared__ ushort_t As[128 * 32];  // 8 KB
    __shared__ ushort_t Bs[128 * 32];  // 8 KB

    const int tid = threadIdx.x;
    const int wave = tid >> 6;
    const int lane = tid & 63;
    const int quad = lane >> 4;
    const int l15 = lane & 15;
    const int rowBase = blockIdx.y * 128;
    const int colBase = blockIdx.x * 128;
    const int wm = (wave >> 1) * 64;
    const int wn = (wave & 1) * 64;

    float4v acc[4][4];
    #pragma unroll
    for (int i = 0; i < 4; ++i)
        #pragma unroll
        for (int j = 0; j < 4; ++j)
            acc[i][j] = (float4v){0.f, 0.f, 0.f, 0.f};

    const int nkt = Ktot / 32;
    const int khalf = K1 / 32;

    for (int kt = 0; kt < nkt; ++kt) {
        const ushort_t* Asrc = A1;
        int kg = kt * 32;
        if (DUAL && kt >= khalf) { Asrc = A2; kg = (kt - khalf) * 32; }
        const int kb = kt * 32;

        #pragma unroll
        for (int u = 0; u < 2; ++u) {
            int c = u * 256 + tid;
            int r = c >> 2, off = (c & 3) * 8;
            int grow = rowBase + r;
            if (grow >= N) grow = N - 1;  // clamp (stores are row-guarded)
            async_copy16(&As[c * 8], Asrc + (size_t)grow * K1 + kg + off);
            async_copy16(&Bs[c * 8], BT + (size_t)(colBase + r) * Ktot + kb + off);
        }
        __syncthreads();

        short8 af[4], bf4[4];
        #pragma unroll
        for (int i = 0; i < 4; ++i)
            af[i] = *(const short8*)&As[(wm + i * 16 + l15) * 32 + quad * 8];
        #pragma unroll
        for (int j = 0; j < 4; ++j)
            bf4[j] = *(const short8*)&Bs[(wn + j * 16 + l15) * 32 + quad * 8];

        // operand swap: acc[i][j][r] = C[wm+i*16+l15][wn+j*16+quad*4+r]
        #pragma unroll
        for (int i = 0; i < 4; ++i)
            #pragma unroll
            for (int j = 0; j < 4; ++j)
                acc[i][j] = __builtin_amdgcn_mfma_f32_16x16x32_bf16(bf4[j], af[i], acc[i][j], 0, 0, 0);
        __syncthreads();
    }

    // epilogue: per-wave 4KB LDS restage -> full-line bf16 stores
    ushort_t* lws = (wave < 2) ? &As[wave * 2048] : &Bs[(wave - 2) * 2048];
    #pragma unroll
    for (int p = 0; p < 2; ++p) {
        #pragma unroll
        for (int jj = 0; jj < 2; ++jj) {
            int j = 2 * p + jj;
            float4 bv = make_float4(0.f, 0.f, 0.f, 0.f);
            if (BIAS) bv = *(const float4*)(bias + colBase + wn + j * 16 + quad * 4);
            #pragma unroll
            for (int i = 0; i < 4; ++i) {
                uint2 pk;
                pk.x = (unsigned int)f2bf(acc[i][j][0] + bv.x) |
                       ((unsigned int)f2bf(acc[i][j][1] + bv.y) << 16);
                pk.y = (unsigned int)f2bf(acc[i][j][2] + bv.z) |
                       ((unsigned int)f2bf(acc[i][j][3] + bv.w) << 16);
                *(uint2*)&lws[(i * 16 + l15) * 32 + jj * 16 + quad * 4] = pk;
            }
        }
        __syncthreads();
        #pragma unroll
        for (int it = 0; it < 4; ++it) {
            int c = it * 64 + lane;
            int row = c >> 2, coff = (c & 3) * 8;
            int grow = rowBase + wm + row;
            if (grow < N) {
                uint4 v = *(const uint4*)&lws[row * 32 + coff];
                *(uint4*)(Cb + (size_t)grow * Wtot + colBase + wn + p * 32 + coff) = v;
            }
        }
        __syncthreads();
    }
}

// ---------------- BN stats (bf16 input) ------------------------------------
// block 256 = 64 col-pairs x 4 row-striders; grid (D/128, 128)
__global__ void colstats_b_kernel(const ushort_t* __restrict__ h, int N, int D,
                                  float* __restrict__ sum, float* __restrict__ sumsq) {
    int c2 = blockIdx.x * 128 + (threadIdx.x & 63) * 2;
    int rl = threadIdx.x >> 6;
    float s0 = 0.f, s20 = 0.f, s1 = 0.f, s21 = 0.f;
    int stride = gridDim.y * 4;
    for (int r = blockIdx.y * 4 + rl; r < N; r += stride) {
        unsigned int w = *(const unsigned int*)(h + (size_t)r * D + c2);
        float v0 = bf2f((ushort_t)(w & 0xffffu));
        float v1 = bf2f((ushort_t)(w >> 16));
        s0 += v0; s20 += v0 * v0;
        s1 += v1; s21 += v1 * v1;
    }
    atomicAdd(&sum[c2 + 0], s0);
    atomicAdd(&sumsq[c2 + 0], s20);
    atomicAdd(&sum[c2 + 1], s1);
    atomicAdd(&sumsq[c2 + 1], s21);
}

// ---------------- BN apply (bf16 in) ---------------------------------------
// bf16 -> bf16 (mid layers)
__global__ void bn_relu_b2b_kernel(const ushort_t* __restrict__ h, ushort_t* __restrict__ hb,
                                   int N, int D,
                                   const float* __restrict__ sum, const float* __restrict__ sumsq,
                                   const float* __restrict__ g, const float* __restrict__ b) {
    size_t idx = (size_t)blockIdx.x * blockDim.x + threadIdx.x;  // uint index
    size_t tot = (size_t)N * D / 2;
    if (idx >= tot) return;
    int cp = (int)(idx & (size_t)(D / 2 - 1));  // col pair
    int c0 = cp * 2, c1 = c0 + 1;
    float m0 = sum[c0] / (float)N, m1 = sum[c1] / (float)N;
    float i0 = rsqrtf(sumsq[c0] / (float)N - m0 * m0 + EPS_BN);
    float i1 = rsqrtf(sumsq[c1] / (float)N - m1 * m1 + EPS_BN);
    unsigned int w = ((const unsigned int*)h)[idx];
    float v0 = g[c0] * (bf2f((ushort_t)(w & 0xffffu)) - m0) * i0 + b[c0];
    float v1 = g[c1] * (bf2f((ushort_t)(w >> 16)) - m1) * i1 + b[c1];
    v0 = v0 > 0.f ? v0 : 0.f;
    v1 = v1 > 0.f ? v1 : 0.f;
    ((unsigned int*)hb)[idx] = (unsigned int)f2bf(v0) | ((unsigned int)f2bf(v1) << 16);
}

// bf16 -> fp32 (final layer -> d_out)
__global__ void bn_relu_b2f_kernel(const ushort_t* __restrict__ h, float* __restrict__ hf,
                                   int N, int D,
                                   const float* __restrict__ sum, const float* __restrict__ sumsq,
                                   const float* __restrict__ g, const float* __restrict__ b) {
    size_t idx = (size_t)blockIdx.x * blockDim.x + threadIdx.x;
    size_t tot = (size_t)N * D / 2;
    if (idx >= tot) return;
    int cp = (int)(idx & (size_t)(D / 2 - 1));
    int c0 = cp * 2, c1 = c0 + 1;
    float m0 = sum[c0] / (float)N, m1 = sum[c1] / (float)N;
    float i0 = rsqrtf(sumsq[c0] / (float)N - m0 * m0 + EPS_BN);
    float i1 = rsqrtf(sumsq[c1] / (float)N - m1 * m1 + EPS_BN);
    unsigned int w = ((const unsigned int*)h)[idx];
    float v0 = g[c0] * (bf2f((ushort_t)(w & 0xffffu)) - m0) * i0 + b[c0];
    float v1 = g[c1] * (bf2f((ushort_t)(w >> 16)) - m1) * i1 + b[c1];
    float2 o;
    o.x = v0 > 0.f ? v0 : 0.f;
    o.y = v1 > 0.f ? v1 : 0.f;
    *(float2*)(hf + idx * 2) = o;
}

// ---------------------------------------------------------------------------
extern "C" void kernel_launch(void* const* d_in, const int* in_sizes, int n_in,
                              void* d_out, int out_size, void* d_ws, size_t ws_size,
                              hipStream_t stream) {
    const float* x     = (const float*)d_in[0];
    const int*   edges = (const int*)d_in[1];
    const float* Wl0 = (const float*)d_in[2];
    const float* bl0 = (const float*)d_in[3];
    const float* Wr0 = (const float*)d_in[4];
    const float* g0  = (const float*)d_in[5];
    const float* b0  = (const float*)d_in[6];
    const float* Wl1 = (const float*)d_in[7];
    const float* bl1 = (const float*)d_in[8];
    const float* Wr1 = (const float*)d_in[9];
    const float* g1  = (const float*)d_in[10];
    const float* b1  = (const float*)d_in[11];
    const float* Wl2 = (const float*)d_in[12];
    const float* bl2 = (const float*)d_in[13];
    const float* Wr2 = (const float*)d_in[14];
    const float* g2  = (const float*)d_in[15];
    const float* b2  = (const float*)d_in[16];

    const int D0 = 128, D1 = 512, D2 = 256, D3 = 128;
    const int n  = in_sizes[0] / D0;   // 50000
    const int ne = in_sizes[1] / 2;    // 800000

    // ---- workspace layout ----
    char* base = (char*)d_ws;
    size_t off = 0;
    auto alloc = [&](size_t bytes) -> char* {
        char* p = base + off;
        off = (off + bytes + 255) & ~(size_t)255;
        return p;
    };
    int*      nzflag  = (int*)alloc(4);
    int*      degi    = (int*)alloc((size_t)n * 4);
    int*      rowptr  = (int*)alloc((size_t)(n + 1) * 4);
    int*      cursor  = (int*)alloc((size_t)n * 4);
    int*      csr_src = (int*)alloc((size_t)ne * 4);
    int*      bsums   = (int*)alloc(64 * 4);
    float*    stats   = (float*)alloc(6 * 512 * 4);
    ushort_t* xb      = (ushort_t*)alloc((size_t)n * D0 * 2);
    ushort_t* mb      = (ushort_t*)alloc((size_t)n * 512 * 2);   // mean(L0) / PR(L1,L2)
    ushort_t* h1b     = (ushort_t*)alloc((size_t)n * D1 * 2);
    ushort_t* h2b     = (ushort_t*)alloc((size_t)n * D2 * 2);
    ushort_t* hpre    = (ushort_t*)alloc((size_t)n * 512 * 2);   // bf16 pre-BN
    ushort_t* WT0     = (ushort_t*)alloc((size_t)D1 * 2 * D0 * 2);
    ushort_t* WT1c    = (ushort_t*)alloc((size_t)(2 * D2) * D1 * 2);
    ushort_t* WT2c    = (ushort_t*)alloc((size_t)(2 * D3) * D2 * 2);
    float*    out     = (float*)d_out;
    (void)ws_size; (void)n_in; (void)out_size;

    hipMemsetAsync(nzflag, 0, 4, stream);
    hipMemsetAsync(degi, 0, (size_t)n * 4, stream);
    hipMemsetAsync(stats, 0, 6 * 512 * 4, stream);

    // ---- edge format detection + CSR build ----
    detect_fmt_kernel<<<1, 256, 0, stream>>>(edges, nzflag);
    count_deg_kernel<<<(ne + 255) / 256, 256, 0, stream>>>(edges, ne, nzflag, degi);
    int nscan = (n + 1023) / 1024;
    scan1_kernel<<<nscan, 1024, 0, stream>>>(degi, n, rowptr, bsums);
    scan2_kernel<<<1, 64, 0, stream>>>(bsums, nscan, rowptr, n, ne);
    scan3_kernel<<<nscan, 1024, 0, stream>>>(rowptr, n, bsums, cursor);
    scatter_kernel<<<(ne + 255) / 256, 256, 0, stream>>>(edges, ne, nzflag, cursor, csr_src);

    // ---- prep: x -> bf16, weights -> transposed bf16 ----
    f2b_kernel<<<((size_t)n * D0 + 255) / 256, 256, 0, stream>>>(x, xb, n * D0);
    prep_wt_kernel<<<(D1 * 2 * D0 + 255) / 256, 256, 0, stream>>>(Wl0, Wr0, WT0, D0, D1);
    prep_wtc_kernel<<<(2 * D2 * D1 + 255) / 256, 256, 0, stream>>>(Wl1, Wr1, WT1c, D1, D2);
    prep_wtc_kernel<<<(2 * D3 * D2 + 255) / 256, 256, 0, stream>>>(Wl2, Wr2, WT2c, D2, D3);

    const int aggGrid = (n + 3) / 4;
    const int rowBlocks = (n + 127) / 128;
    float* st0 = stats + 0 * 1024;
    float* st1 = stats + 1 * 1024;
    float* st2 = stats + 2 * 1024;

    // ---- layer 0: 128 -> 512 (aggregate-first: din < dout) ----
    aggregate_wave_kernel<2><<<aggGrid, 256, 0, stream>>>(xb, mb, rowptr, csr_src, n);
    gemm_glds_kernel<true, true><<<dim3(D1 / 128, rowBlocks), 256, 0, stream>>>(
        mb, xb, WT0, bl0, hpre, n, D0, 2 * D0, D1);
    colstats_b_kernel<<<dim3(D1 / 128, 128), 256, 0, stream>>>(hpre, n, D1, st0, st0 + 512);
    bn_relu_b2b_kernel<<<((size_t)n * D1 / 2 + 255) / 256, 256, 0, stream>>>(
        hpre, h1b, n, D1, st0, st0 + 512, g0, b0);

    // ---- layer 1: 512 -> 256 (project-first, fused [P|R]) ----
    gemm_glds_kernel<false, false><<<dim3(2 * D2 / 128, rowBlocks), 256, 0, stream>>>(
        h1b, nullptr, WT1c, nullptr, mb, n, D1, D1, 2 * D2);      // PR1 = h1 @ [Wl1|Wr1]
    aggregate_add_kernel<4><<<aggGrid, 256, 0, stream>>>(
        mb, bl1, hpre, rowptr, csr_src, n);                        // pre = mean(P)+R+bl1
    colstats_b_kernel<<<dim3(D2 / 128, 128), 256, 0, stream>>>(hpre, n, D2, st1, st1 + 512);
    bn_relu_b2b_kernel<<<((size_t)n * D2 / 2 + 255) / 256, 256, 0, stream>>>(
        hpre, h2b, n, D2, st1, st1 + 512, g1, b1);

    // ---- layer 2: 256 -> 128 (project-first, fused [P|R]) ----
    gemm_glds_kernel<false, false><<<dim3(2 * D3 / 128, rowBlocks), 256, 0, stream>>>(
        h2b, nullptr, WT2c, nullptr, mb, n, D2, D2, 2 * D3);      // PR2 = h2 @ [Wl2|Wr2]
    aggregate_add_kernel<2><<<aggGrid, 256, 0, stream>>>(
        mb, bl2, hpre, rowptr, csr_src, n);                        // pre = mean(P)+R+bl2
    colstats_b_kernel<<<dim3(D3 / 128, 128), 256, 0, stream>>>(hpre, n, D3, st2, st2 + 512);
    bn_relu_b2f_kernel<<<((size_t)n * D3 / 2 + 255) / 256, 256, 0, stream>>>(
        hpre, out, n, D3, st2, st2 + 512, g2, b2);
}